// Round 8
// baseline (401.744 us; speedup 1.0000x reference)
//
#include <hip/hip_runtime.h>
#include <math.h>

constexpr int BLK = 256;
constexpr int NB_MAX = 256;      // max coarse buckets (supports N <= 131072)
constexpr int BSHIFT = 9;        // 512 nodes per bucket
constexpr int BSPAN = 1 << BSHIFT;
constexpr int CAP = 10240;       // per-bucket bin capacity (mean 8192 @ E=1.6M)
constexpr int EPT2 = 16;         // edges per thread in binpass
constexpr int EPBB = BLK * EPT2; // 4096 edges per block

typedef unsigned short u16;

// ---- bf16 helpers (storage-only precision reduction for gather arrays) ----
__device__ __forceinline__ float bf2f(u16 u) {
  union { unsigned int i; float f; } v;
  v.i = ((unsigned int)u) << 16;
  return v.f;
}
__device__ __forceinline__ u16 f2bf(float f) {
  union { float f; unsigned int i; } v;
  v.f = f;
  unsigned int r = v.i + 0x7FFF + ((v.i >> 16) & 1);  // RNE
  return (u16)(r >> 16);
}

// ---------------- pass 1: coarse binning into block-private chunks ----------------
__global__ void __launch_bounds__(BLK) binpass(const int* __restrict__ src,
                                               const int* __restrict__ dst,
                                               int e, int* __restrict__ bins,
                                               int* __restrict__ tail) {
  __shared__ int lcnt[NB_MAX], gbase[NB_MAX], lcur[NB_MAX];
  const int tid = threadIdx.x;
  lcnt[tid] = 0;
  lcur[tid] = 0;
  __syncthreads();
  const int i0 = blockIdx.x * EPBB;
  int bb[EPT2], pk[EPT2];
#pragma unroll
  for (int k = 0; k < EPT2; k++) {
    int i = i0 + k * BLK + tid;
    if (i < e) {
      int d = dst[i], s = src[i];
      bb[k] = d >> BSHIFT;
      pk[k] = ((d & (BSPAN - 1)) << 23) | s;   // src < 2^23, dlo < 2^9
      atomicAdd(&lcnt[bb[k]], 1);
    } else {
      bb[k] = -1;
    }
  }
  __syncthreads();
  gbase[tid] = atomicAdd(&tail[tid], lcnt[tid]);  // reserve contiguous chunk per bucket
  __syncthreads();
#pragma unroll
  for (int k = 0; k < EPT2; k++) {
    if (bb[k] >= 0) {
      int idx = atomicAdd(&lcur[bb[k]], 1);
      bins[bb[k] * CAP + gbase[bb[k]] + idx] = pk[k];
    }
  }
}

// ---------------- pass 2: exclusive scan of bucket totals ----------------
__global__ void __launch_bounds__(BLK) scan256(const int* __restrict__ tail,
                                               int* __restrict__ bbase,
                                               int* __restrict__ row_ptr,
                                               int n, int e) {
  __shared__ int sd[BLK];
  int v = tail[threadIdx.x];
  sd[threadIdx.x] = v;
  __syncthreads();
  for (int off = 1; off < BLK; off <<= 1) {
    int t = (threadIdx.x >= off) ? sd[threadIdx.x - off] : 0;
    __syncthreads();
    sd[threadIdx.x] += t;
    __syncthreads();
  }
  bbase[threadIdx.x] = sd[threadIdx.x] - v;
  if (threadIdx.x == 0) row_ptr[n] = e;
}

// ---------------- pass 3: per-bucket counting sort (block-private col region) ----------------
__global__ void __launch_bounds__(BLK) bucket_sort(const int* __restrict__ bins,
                                                   const int* __restrict__ tail,
                                                   const int* __restrict__ bbase,
                                                   int* __restrict__ row_ptr,
                                                   int* __restrict__ col,
                                                   float* __restrict__ dinv, int n) {
  __shared__ int hist[BSPAN], lpre[BSPAN], lcur[BSPAN], sd[BLK];
  const int b = blockIdx.x, tid = threadIdx.x;
  const int cnt = tail[b];
  const int base = bbase[b];
  const int node0 = b << BSHIFT;
  const int nNodes = min(BSPAN, n - node0);
  const int* bin = bins + (size_t)b * CAP;

  hist[tid] = 0; hist[tid + BLK] = 0;
  lcur[tid] = 0; lcur[tid + BLK] = 0;
  __syncthreads();
  for (int j = tid; j < cnt; j += BLK) atomicAdd(&hist[(unsigned)bin[j] >> 23], 1);
  __syncthreads();
  // exclusive scan over 512 counters (2 per thread)
  int v0 = hist[2 * tid], v1 = hist[2 * tid + 1], ts = v0 + v1;
  sd[tid] = ts;
  __syncthreads();
  for (int off = 1; off < BLK; off <<= 1) {
    int t = (tid >= off) ? sd[tid - off] : 0;
    __syncthreads();
    sd[tid] += t;
    __syncthreads();
  }
  int ex = sd[tid] - ts;
  lpre[2 * tid] = ex;
  lpre[2 * tid + 1] = ex + v0;
  __syncthreads();
  for (int d = tid; d < nNodes; d += BLK) {
    row_ptr[node0 + d] = base + lpre[d];
    dinv[node0 + d] = rsqrtf((float)hist[d] + 1.0f);
  }
  for (int j = tid; j < cnt; j += BLK) {
    int pkv = bin[j];
    int dlo = (unsigned)pkv >> 23;
    int idx = atomicAdd(&lcur[dlo], 1);
    col[base + lpre[dlo] + idx] = pkv & 0x7FFFFF;
  }
}

// ---------------- dense GEMM: G[n][M] = bf16((X[n][K] @ W[K][M]) * dinv[n]) ----------------
// r5 structure + C=2 cols/thread. 256 threads = CP col-pairs x GROUPS row-groups,
// each thread R rows x 2 cols. X staged full-K coalesced, stride K+4 (16B aligned;
// wave reads 2-4 row-addrs on same bank quad = 2-way free, 16-lane broadcast).
// W staged in KS-chunks. ~2.5 B/FMA LDS traffic; 49.8KB LDS -> 3 blocks/CU.
template <int K, int M, int R, int KS>
__global__ void __launch_bounds__(BLK, 4) gemm_c2(const float* __restrict__ X,
                                                  const float* __restrict__ W,
                                                  const float* __restrict__ dinv,
                                                  u16* __restrict__ G, int n) {
  constexpr int CP = M / 2;          // col-pairs
  constexpr int GROUPS = BLK / CP;   // row groups
  constexpr int ROWS = GROUPS * R;
  __shared__ float xs[ROWS][K + 4];
  __shared__ float ws[KS][M];
  const int tid = threadIdx.x;
  const int row0 = blockIdx.x * ROWS;
  const int cp = tid % CP;
  const int grp = tid / CP;

  // stage X (full K), coalesced: 32 consecutive lanes cover one 512B row
  constexpr int XTOT = ROWS * K;
#pragma unroll
  for (int i = tid * 4; i < XTOT; i += BLK * 4) {
    int r = i / K, c = i % K;
    int gr = row0 + r;
    if (gr >= n) gr = n - 1;  // clamp (stores guarded)
    *(float4*)&xs[r][c] = *(const float4*)&X[(size_t)gr * K + c];
  }

  float acc[R][2];
#pragma unroll
  for (int r = 0; r < R; r++) { acc[r][0] = 0.f; acc[r][1] = 0.f; }

  for (int ks = 0; ks < K; ks += KS) {
    __syncthreads();  // covers xs stage (iter 0) and ws re-stage
#pragma unroll
    for (int i = tid * 4; i < KS * M; i += BLK * 4)
      *(float4*)&((float*)ws)[i] = *(const float4*)&W[(size_t)ks * M + i];
    __syncthreads();
#pragma unroll
    for (int k4 = 0; k4 < KS; k4 += 4) {
      float4 xa[R];
#pragma unroll
      for (int r = 0; r < R; r++) xa[r] = *(const float4*)&xs[grp * R + r][ks + k4];
      float2 wA = *(const float2*)&ws[k4 + 0][cp * 2];
      float2 wB = *(const float2*)&ws[k4 + 1][cp * 2];
      float2 wC = *(const float2*)&ws[k4 + 2][cp * 2];
      float2 wD = *(const float2*)&ws[k4 + 3][cp * 2];
#pragma unroll
      for (int r = 0; r < R; r++) {
        acc[r][0] += xa[r].x * wA.x + xa[r].y * wB.x + xa[r].z * wC.x + xa[r].w * wD.x;
        acc[r][1] += xa[r].x * wA.y + xa[r].y * wB.y + xa[r].z * wC.y + xa[r].w * wD.y;
      }
    }
  }

#pragma unroll
  for (int r = 0; r < R; r++) {
    int gr = row0 + grp * R + r;
    if (gr < n) {
      float s = dinv[gr];
      unsigned pack = (unsigned)f2bf(acc[r][0] * s) | ((unsigned)f2bf(acc[r][1] * s) << 16);
      *(unsigned*)&G[(size_t)gr * M + cp * 2] = pack;
    }
  }
}

// ---------------- aggregation ----------------
// gs (bf16) holds (X@W)*dinv[row]. out[i] = relu(dinv[i]*(gs[i] + sum_s gs[s]) + b)

__global__ void __launch_bounds__(BLK) agg1_kernel(const u16* __restrict__ gs,
                                                   const int* __restrict__ row_ptr,
                                                   const int* __restrict__ col,
                                                   const float* __restrict__ dinv,
                                                   const float* __restrict__ bias,
                                                   float* __restrict__ out, int n) {
  int node = (blockIdx.x * BLK + threadIdx.x) >> 6;
  int lane = threadIdx.x & 63;
  if (node >= n) return;
  int beg = row_ptr[node], end = row_ptr[node + 1];
  float acc = bf2f(gs[(size_t)node * 64 + lane]);  // self-loop (prescaled)
  int e1 = end - 1;
  for (int j = beg; j < end; j += 8) {
    int s[8];
#pragma unroll
    for (int t = 0; t < 8; t++) {
      int jj = j + t;
      s[t] = col[jj <= e1 ? jj : e1];
    }
    float a[8];
#pragma unroll
    for (int t = 0; t < 8; t++) a[t] = bf2f(gs[(size_t)s[t] * 64 + lane]);
#pragma unroll
    for (int t = 0; t < 8; t++) acc += (j + t <= e1) ? a[t] : 0.f;
  }
  float v = acc * dinv[node] + bias[lane];
  out[(size_t)node * 64 + lane] = v > 0.f ? v : 0.f;
}

__global__ void __launch_bounds__(BLK) agg2_kernel(const u16* __restrict__ gs,
                                                   const int* __restrict__ row_ptr,
                                                   const int* __restrict__ col,
                                                   const float* __restrict__ dinv,
                                                   const float* __restrict__ bias,
                                                   float* __restrict__ out, int n) {
  int node = (blockIdx.x * BLK + threadIdx.x) >> 6;
  int lane = threadIdx.x & 63;
  if (node >= n) return;
  int c = lane & 31, half = lane >> 5;
  float acc = (half == 0) ? bf2f(gs[(size_t)node * 32 + c]) : 0.f;
  int beg = row_ptr[node], end = row_ptr[node + 1];
  int e1 = end - 1;
  for (int j = beg + half; j < end; j += 8) {
    int s[4];
#pragma unroll
    for (int t = 0; t < 4; t++) {
      int jj = j + 2 * t;
      s[t] = col[jj <= e1 ? jj : e1];
    }
    float a[4];
#pragma unroll
    for (int t = 0; t < 4; t++) a[t] = bf2f(gs[(size_t)s[t] * 32 + c]);
#pragma unroll
    for (int t = 0; t < 4; t++) acc += (j + 2 * t <= e1) ? a[t] : 0.f;
  }
  acc += __shfl_xor(acc, 32);
  if (half == 0) {
    float v = acc * dinv[node] + bias[c];
    out[(size_t)node * 32 + c] = v > 0.f ? v : 0.f;
  }
}

// ---------------- launcher ----------------

extern "C" void kernel_launch(void* const* d_in, const int* in_sizes, int n_in,
                              void* d_out, int out_size, void* d_ws, size_t ws_size,
                              hipStream_t stream) {
  const float* x = (const float*)d_in[0];
  const int* ei = (const int*)d_in[1];
  const float* W1 = (const float*)d_in[2];
  const float* b1 = (const float*)d_in[3];
  const float* W2 = (const float*)d_in[4];
  const float* b2 = (const float*)d_in[5];

  const int N = in_sizes[0] / 128;
  const int E = in_sizes[1] / 2;
  const int* src = ei;
  const int* dst = ei + E;
  const int nb = (N + BSPAN - 1) >> BSHIFT;  // # coarse buckets (196 @ N=100K)

  char* p = (char*)d_ws;
  auto take = [&](size_t bytes) -> char* {
    char* q = p;
    p += (bytes + 255) & ~(size_t)255;
    return q;
  };
  int* bins = (int*)take((size_t)NB_MAX * CAP * 4);
  int* tail = (int*)take(NB_MAX * 4);
  int* bbase = (int*)take(NB_MAX * 4);
  int* row_ptr = (int*)take((size_t)(N + 1) * 4);
  int* col = (int*)take((size_t)E * 4);
  float* dinv = (float*)take((size_t)N * 4);
  u16* g1 = (u16*)take((size_t)N * 64 * 2);
  float* h = (float*)take((size_t)N * 64 * 4);
  u16* g2 = (u16*)take((size_t)N * 32 * 2);

  hipMemsetAsync(tail, 0, NB_MAX * 4, stream);

  binpass<<<(E + EPBB - 1) / EPBB, BLK, 0, stream>>>(src, dst, E, bins, tail);
  scan256<<<1, BLK, 0, stream>>>(tail, bbase, row_ptr, N, E);
  bucket_sort<<<nb, BLK, 0, stream>>>(bins, tail, bbase, row_ptr, col, dinv, N);

  // gemm1: CP=32, GROUPS=8, R=8 -> ROWS=64; LDS 33.8+16 = 49.8KB, grid 1563
  gemm_c2<128, 64, 8, 64><<<(N + 63) / 64, BLK, 0, stream>>>(x, W1, dinv, g1, N);
  agg1_kernel<<<(N + 3) / 4, BLK, 0, stream>>>(g1, row_ptr, col, dinv, b1, h, N);
  // gemm2: CP=16, GROUPS=16, R=4 -> ROWS=64; LDS 17.4+8 = 25.4KB, grid 1563
  gemm_c2<64, 32, 4, 64><<<(N + 63) / 64, BLK, 0, stream>>>(h, W2, dinv, g2, N);
  agg2_kernel<<<(N + 3) / 4, BLK, 0, stream>>>(g2, row_ptr, col, dinv, b2, (float*)d_out, N);
}

// Round 9
// 216.087 us; speedup vs baseline: 1.8592x; 1.8592x over previous
//
#include <hip/hip_runtime.h>
#include <math.h>

constexpr int BLK = 256;
constexpr int NB_MAX = 256;      // max coarse buckets (supports N <= 131072)
constexpr int BSHIFT = 9;        // 512 nodes per bucket
constexpr int BSPAN = 1 << BSHIFT;
constexpr int CAP = 10240;       // per-bucket bin capacity (mean 8192 @ E=1.6M)
constexpr int EPT2 = 16;         // edges per thread in binpass
constexpr int EPBB = BLK * EPT2; // 4096 edges per block

typedef unsigned short u16;

// ---- bf16 helpers (storage-only precision reduction for gather arrays) ----
__device__ __forceinline__ float bf2f(u16 u) {
  union { unsigned int i; float f; } v;
  v.i = ((unsigned int)u) << 16;
  return v.f;
}
__device__ __forceinline__ u16 f2bf(float f) {
  union { float f; unsigned int i; } v;
  v.f = f;
  unsigned int r = v.i + 0x7FFF + ((v.i >> 16) & 1);  // RNE
  return (u16)(r >> 16);
}

// ---------------- pass 1: coarse binning into block-private chunks ----------------
__global__ void __launch_bounds__(BLK) binpass(const int* __restrict__ src,
                                               const int* __restrict__ dst,
                                               int e, int* __restrict__ bins,
                                               int* __restrict__ tail) {
  __shared__ int lcnt[NB_MAX], gbase[NB_MAX], lcur[NB_MAX];
  const int tid = threadIdx.x;
  lcnt[tid] = 0;
  lcur[tid] = 0;
  __syncthreads();
  const int i0 = blockIdx.x * EPBB;
  int bb[EPT2], pk[EPT2];
#pragma unroll
  for (int k = 0; k < EPT2; k++) {
    int i = i0 + k * BLK + tid;
    if (i < e) {
      int d = dst[i], s = src[i];
      bb[k] = d >> BSHIFT;
      pk[k] = ((d & (BSPAN - 1)) << 23) | s;   // src < 2^23, dlo < 2^9
      atomicAdd(&lcnt[bb[k]], 1);
    } else {
      bb[k] = -1;
    }
  }
  __syncthreads();
  gbase[tid] = atomicAdd(&tail[tid], lcnt[tid]);  // reserve contiguous chunk per bucket
  __syncthreads();
#pragma unroll
  for (int k = 0; k < EPT2; k++) {
    if (bb[k] >= 0) {
      int idx = atomicAdd(&lcur[bb[k]], 1);
      bins[bb[k] * CAP + gbase[bb[k]] + idx] = pk[k];
    }
  }
}

// ---------------- pass 2: exclusive scan of bucket totals ----------------
__global__ void __launch_bounds__(BLK) scan256(const int* __restrict__ tail,
                                               int* __restrict__ bbase,
                                               int* __restrict__ row_ptr,
                                               int n, int e) {
  __shared__ int sd[BLK];
  int v = tail[threadIdx.x];
  sd[threadIdx.x] = v;
  __syncthreads();
  for (int off = 1; off < BLK; off <<= 1) {
    int t = (threadIdx.x >= off) ? sd[threadIdx.x - off] : 0;
    __syncthreads();
    sd[threadIdx.x] += t;
    __syncthreads();
  }
  bbase[threadIdx.x] = sd[threadIdx.x] - v;
  if (threadIdx.x == 0) row_ptr[n] = e;
}

// ---------------- pass 3: per-bucket counting sort (block-private col region) ----------------
__global__ void __launch_bounds__(BLK) bucket_sort(const int* __restrict__ bins,
                                                   const int* __restrict__ tail,
                                                   const int* __restrict__ bbase,
                                                   int* __restrict__ row_ptr,
                                                   int* __restrict__ col,
                                                   float* __restrict__ dinv, int n) {
  __shared__ int hist[BSPAN], lpre[BSPAN], lcur[BSPAN], sd[BLK];
  const int b = blockIdx.x, tid = threadIdx.x;
  const int cnt = tail[b];
  const int base = bbase[b];
  const int node0 = b << BSHIFT;
  const int nNodes = min(BSPAN, n - node0);
  const int* bin = bins + (size_t)b * CAP;

  hist[tid] = 0; hist[tid + BLK] = 0;
  lcur[tid] = 0; lcur[tid + BLK] = 0;
  __syncthreads();
  for (int j = tid; j < cnt; j += BLK) atomicAdd(&hist[(unsigned)bin[j] >> 23], 1);
  __syncthreads();
  // exclusive scan over 512 counters (2 per thread)
  int v0 = hist[2 * tid], v1 = hist[2 * tid + 1], ts = v0 + v1;
  sd[tid] = ts;
  __syncthreads();
  for (int off = 1; off < BLK; off <<= 1) {
    int t = (tid >= off) ? sd[tid - off] : 0;
    __syncthreads();
    sd[tid] += t;
    __syncthreads();
  }
  int ex = sd[tid] - ts;
  lpre[2 * tid] = ex;
  lpre[2 * tid + 1] = ex + v0;
  __syncthreads();
  for (int d = tid; d < nNodes; d += BLK) {
    row_ptr[node0 + d] = base + lpre[d];
    dinv[node0 + d] = rsqrtf((float)hist[d] + 1.0f);
  }
  for (int j = tid; j < cnt; j += BLK) {
    int pkv = bin[j];
    int dlo = (unsigned)pkv >> 23;
    int idx = atomicAdd(&lcur[dlo], 1);
    col[base + lpre[dlo] + idx] = pkv & 0x7FFFFF;
  }
}

// ---------------- dense GEMM: G[n][M] = bf16((X[n][K] @ W[K][M]) * dinv[n]) ----------------
// 256 threads = CP col-pairs x GROUPS row-groups; each thread R rows x 2 cols.
// X staged full-K coalesced (stride K+4); W staged in KS chunks. ~2.25 B/FMA LDS
// traffic. NO min-waves clamp (r8 lesson: VGPR cap below live set -> scratch
// spill, 670MB of HBM traffic). Small live set: w-pairs + one xa per FMA step.
template <int K, int M, int R, int KS>
__global__ void __launch_bounds__(BLK) gemm_c2(const float* __restrict__ X,
                                               const float* __restrict__ W,
                                               const float* __restrict__ dinv,
                                               u16* __restrict__ G, int n) {
  constexpr int CP = M / 2;          // col-pairs
  constexpr int GROUPS = BLK / CP;   // row groups
  constexpr int ROWS = GROUPS * R;
  __shared__ float xs[ROWS][K + 4];
  __shared__ float ws[KS][M];
  const int tid = threadIdx.x;
  const int row0 = blockIdx.x * ROWS;
  const int cp = tid % CP;
  const int grp = tid / CP;

  // stage X (full K), coalesced: 32 consecutive lanes cover one 512B row
  constexpr int XTOT = ROWS * K;
  for (int i = tid * 4; i < XTOT; i += BLK * 4) {
    int r = i / K, c = i % K;
    int gr = row0 + r;
    if (gr >= n) gr = n - 1;  // clamp (stores guarded)
    *(float4*)&xs[r][c] = *(const float4*)&X[(size_t)gr * K + c];
  }

  float acc[R][2];
#pragma unroll
  for (int r = 0; r < R; r++) { acc[r][0] = 0.f; acc[r][1] = 0.f; }

  for (int ks = 0; ks < K; ks += KS) {
    __syncthreads();  // covers xs stage (iter 0) and ws re-stage
    for (int i = tid * 4; i < KS * M; i += BLK * 4)
      *(float4*)&((float*)ws)[i] = *(const float4*)&W[(size_t)ks * M + i];
    __syncthreads();
    for (int k4 = 0; k4 < KS; k4 += 4) {
      const float2 wA = *(const float2*)&ws[k4 + 0][cp * 2];
      const float2 wB = *(const float2*)&ws[k4 + 1][cp * 2];
      const float2 wC = *(const float2*)&ws[k4 + 2][cp * 2];
      const float2 wD = *(const float2*)&ws[k4 + 3][cp * 2];
#pragma unroll
      for (int r = 0; r < R; r++) {
        const float4 xa = *(const float4*)&xs[grp * R + r][ks + k4];
        acc[r][0] += xa.x * wA.x + xa.y * wB.x + xa.z * wC.x + xa.w * wD.x;
        acc[r][1] += xa.x * wA.y + xa.y * wB.y + xa.z * wC.y + xa.w * wD.y;
      }
    }
  }

#pragma unroll
  for (int r = 0; r < R; r++) {
    int gr = row0 + grp * R + r;
    if (gr < n) {
      float s = dinv[gr];
      unsigned pack = (unsigned)f2bf(acc[r][0] * s) | ((unsigned)f2bf(acc[r][1] * s) << 16);
      *(unsigned*)&G[(size_t)gr * M + cp * 2] = pack;
    }
  }
}

// ---------------- aggregation ----------------
// gs (bf16) holds (X@W)*dinv[row]. out[i] = relu(dinv[i]*(gs[i] + sum_s gs[s]) + b)

__global__ void __launch_bounds__(BLK) agg1_kernel(const u16* __restrict__ gs,
                                                   const int* __restrict__ row_ptr,
                                                   const int* __restrict__ col,
                                                   const float* __restrict__ dinv,
                                                   const float* __restrict__ bias,
                                                   float* __restrict__ out, int n) {
  int node = (blockIdx.x * BLK + threadIdx.x) >> 6;
  int lane = threadIdx.x & 63;
  if (node >= n) return;
  int beg = row_ptr[node], end = row_ptr[node + 1];
  float acc = bf2f(gs[(size_t)node * 64 + lane]);  // self-loop (prescaled)
  int e1 = end - 1;
  for (int j = beg; j < end; j += 8) {
    int s[8];
#pragma unroll
    for (int t = 0; t < 8; t++) {
      int jj = j + t;
      s[t] = col[jj <= e1 ? jj : e1];
    }
    float a[8];
#pragma unroll
    for (int t = 0; t < 8; t++) a[t] = bf2f(gs[(size_t)s[t] * 64 + lane]);
#pragma unroll
    for (int t = 0; t < 8; t++) acc += (j + t <= e1) ? a[t] : 0.f;
  }
  float v = acc * dinv[node] + bias[lane];
  out[(size_t)node * 64 + lane] = v > 0.f ? v : 0.f;
}

__global__ void __launch_bounds__(BLK) agg2_kernel(const u16* __restrict__ gs,
                                                   const int* __restrict__ row_ptr,
                                                   const int* __restrict__ col,
                                                   const float* __restrict__ dinv,
                                                   const float* __restrict__ bias,
                                                   float* __restrict__ out, int n) {
  int node = (blockIdx.x * BLK + threadIdx.x) >> 6;
  int lane = threadIdx.x & 63;
  if (node >= n) return;
  int c = lane & 31, half = lane >> 5;
  float acc = (half == 0) ? bf2f(gs[(size_t)node * 32 + c]) : 0.f;
  int beg = row_ptr[node], end = row_ptr[node + 1];
  int e1 = end - 1;
  for (int j = beg + half; j < end; j += 8) {
    int s[4];
#pragma unroll
    for (int t = 0; t < 4; t++) {
      int jj = j + 2 * t;
      s[t] = col[jj <= e1 ? jj : e1];
    }
    float a[4];
#pragma unroll
    for (int t = 0; t < 4; t++) a[t] = bf2f(gs[(size_t)s[t] * 32 + c]);
#pragma unroll
    for (int t = 0; t < 4; t++) acc += (j + 2 * t <= e1) ? a[t] : 0.f;
  }
  acc += __shfl_xor(acc, 32);
  if (half == 0) {
    float v = acc * dinv[node] + bias[c];
    out[(size_t)node * 32 + c] = v > 0.f ? v : 0.f;
  }
}

// ---------------- launcher ----------------

extern "C" void kernel_launch(void* const* d_in, const int* in_sizes, int n_in,
                              void* d_out, int out_size, void* d_ws, size_t ws_size,
                              hipStream_t stream) {
  const float* x = (const float*)d_in[0];
  const int* ei = (const int*)d_in[1];
  const float* W1 = (const float*)d_in[2];
  const float* b1 = (const float*)d_in[3];
  const float* W2 = (const float*)d_in[4];
  const float* b2 = (const float*)d_in[5];

  const int N = in_sizes[0] / 128;
  const int E = in_sizes[1] / 2;
  const int* src = ei;
  const int* dst = ei + E;
  const int nb = (N + BSPAN - 1) >> BSHIFT;  // # coarse buckets (196 @ N=100K)

  char* p = (char*)d_ws;
  auto take = [&](size_t bytes) -> char* {
    char* q = p;
    p += (bytes + 255) & ~(size_t)255;
    return q;
  };
  int* bins = (int*)take((size_t)NB_MAX * CAP * 4);
  int* tail = (int*)take(NB_MAX * 4);
  int* bbase = (int*)take(NB_MAX * 4);
  int* row_ptr = (int*)take((size_t)(N + 1) * 4);
  int* col = (int*)take((size_t)E * 4);
  float* dinv = (float*)take((size_t)N * 4);
  u16* g1 = (u16*)take((size_t)N * 64 * 2);
  float* h = (float*)take((size_t)N * 64 * 4);
  u16* g2 = (u16*)take((size_t)N * 32 * 2);

  hipMemsetAsync(tail, 0, NB_MAX * 4, stream);

  binpass<<<(E + EPBB - 1) / EPBB, BLK, 0, stream>>>(src, dst, E, bins, tail);
  scan256<<<1, BLK, 0, stream>>>(tail, bbase, row_ptr, N, E);
  bucket_sort<<<nb, BLK, 0, stream>>>(bins, tail, bbase, row_ptr, col, dinv, N);

  // gemm1: CP=32, GROUPS=8, R=8 -> ROWS=64; LDS 33.8+16 = 49KB, grid 1563
  gemm_c2<128, 64, 8, 64><<<(N + 63) / 64, BLK, 0, stream>>>(x, W1, dinv, g1, N);
  agg1_kernel<<<(N + 3) / 4, BLK, 0, stream>>>(g1, row_ptr, col, dinv, b1, h, N);
  // gemm2: CP=16, GROUPS=16, R=4 -> ROWS=64; LDS 17.4+8 = 25.6KB, grid 1563
  gemm_c2<64, 32, 4, 64><<<(N + 63) / 64, BLK, 0, stream>>>(h, W2, dinv, g2, N);
  agg2_kernel<<<(N + 3) / 4, BLK, 0, stream>>>(g2, row_ptr, col, dinv, b2, (float*)d_out, N);
}

// Round 10
// 214.278 us; speedup vs baseline: 1.8749x; 1.0084x over previous
//
#include <hip/hip_runtime.h>
#include <math.h>

constexpr int BLK = 256;
constexpr int NB_MAX = 256;      // max coarse buckets (supports N <= 131072)
constexpr int BSHIFT = 9;        // 512 nodes per bucket
constexpr int BSPAN = 1 << BSHIFT;
constexpr int CAP = 10240;       // per-bucket bin capacity (mean 8192 @ E=1.6M)
constexpr int EPT2 = 16;         // edges per thread in binpass
constexpr int EPBB = BLK * EPT2; // 4096 edges per block

typedef unsigned short u16;

// ---- bf16 helpers ----
__device__ __forceinline__ u16 f2bf(float f) {
  union { float f; unsigned int i; } v;
  v.f = f;
  unsigned int r = v.i + 0x7FFF + ((v.i >> 16) & 1);  // RNE
  return (u16)(r >> 16);
}
__device__ __forceinline__ float bf2f(u16 u) {
  union { unsigned int i; float f; } v;
  v.i = ((unsigned int)u) << 16;
  return v.f;
}
__device__ __forceinline__ float bf_lo(unsigned u) {
  union { unsigned int i; float f; } v;
  v.i = u << 16;
  return v.f;
}
__device__ __forceinline__ float bf_hi(unsigned u) {
  union { unsigned int i; float f; } v;
  v.i = u & 0xFFFF0000u;
  return v.f;
}

// ---------------- pass 1: coarse binning into block-private chunks ----------------
__global__ void __launch_bounds__(BLK) binpass(const int* __restrict__ src,
                                               const int* __restrict__ dst,
                                               int e, int* __restrict__ bins,
                                               int* __restrict__ tail) {
  __shared__ int lcnt[NB_MAX], gbase[NB_MAX], lcur[NB_MAX];
  const int tid = threadIdx.x;
  lcnt[tid] = 0;
  lcur[tid] = 0;
  __syncthreads();
  const int i0 = blockIdx.x * EPBB;
  int bb[EPT2], pk[EPT2];
#pragma unroll
  for (int k = 0; k < EPT2; k++) {
    int i = i0 + k * BLK + tid;
    if (i < e) {
      int d = dst[i], s = src[i];
      bb[k] = d >> BSHIFT;
      pk[k] = ((d & (BSPAN - 1)) << 23) | s;   // src < 2^23, dlo < 2^9
      atomicAdd(&lcnt[bb[k]], 1);
    } else {
      bb[k] = -1;
    }
  }
  __syncthreads();
  gbase[tid] = atomicAdd(&tail[tid], lcnt[tid]);  // reserve contiguous chunk per bucket
  __syncthreads();
#pragma unroll
  for (int k = 0; k < EPT2; k++) {
    if (bb[k] >= 0) {
      int idx = atomicAdd(&lcur[bb[k]], 1);
      bins[bb[k] * CAP + gbase[bb[k]] + idx] = pk[k];
    }
  }
}

// ---------------- pass 2: exclusive scan of bucket totals ----------------
__global__ void __launch_bounds__(BLK) scan256(const int* __restrict__ tail,
                                               int* __restrict__ bbase,
                                               int* __restrict__ row_ptr,
                                               int n, int e) {
  __shared__ int sd[BLK];
  int v = tail[threadIdx.x];
  sd[threadIdx.x] = v;
  __syncthreads();
  for (int off = 1; off < BLK; off <<= 1) {
    int t = (threadIdx.x >= off) ? sd[threadIdx.x - off] : 0;
    __syncthreads();
    sd[threadIdx.x] += t;
    __syncthreads();
  }
  bbase[threadIdx.x] = sd[threadIdx.x] - v;
  if (threadIdx.x == 0) row_ptr[n] = e;
}

// ---------------- pass 3: per-bucket counting sort (block-private col region) ----------------
__global__ void __launch_bounds__(BLK) bucket_sort(const int* __restrict__ bins,
                                                   const int* __restrict__ tail,
                                                   const int* __restrict__ bbase,
                                                   int* __restrict__ row_ptr,
                                                   int* __restrict__ col,
                                                   float* __restrict__ dinv, int n) {
  __shared__ int hist[BSPAN], lpre[BSPAN], lcur[BSPAN], sd[BLK];
  const int b = blockIdx.x, tid = threadIdx.x;
  const int cnt = tail[b];
  const int base = bbase[b];
  const int node0 = b << BSHIFT;
  const int nNodes = min(BSPAN, n - node0);
  const int* bin = bins + (size_t)b * CAP;

  hist[tid] = 0; hist[tid + BLK] = 0;
  lcur[tid] = 0; lcur[tid + BLK] = 0;
  __syncthreads();
  for (int j = tid; j < cnt; j += BLK) atomicAdd(&hist[(unsigned)bin[j] >> 23], 1);
  __syncthreads();
  // exclusive scan over 512 counters (2 per thread)
  int v0 = hist[2 * tid], v1 = hist[2 * tid + 1], ts = v0 + v1;
  sd[tid] = ts;
  __syncthreads();
  for (int off = 1; off < BLK; off <<= 1) {
    int t = (tid >= off) ? sd[tid - off] : 0;
    __syncthreads();
    sd[tid] += t;
    __syncthreads();
  }
  int ex = sd[tid] - ts;
  lpre[2 * tid] = ex;
  lpre[2 * tid + 1] = ex + v0;
  __syncthreads();
  for (int d = tid; d < nNodes; d += BLK) {
    row_ptr[node0 + d] = base + lpre[d];
    dinv[node0 + d] = rsqrtf((float)hist[d] + 1.0f);
  }
  for (int j = tid; j < cnt; j += BLK) {
    int pkv = bin[j];
    int dlo = (unsigned)pkv >> 23;
    int idx = atomicAdd(&lcur[dlo], 1);
    col[base + lpre[dlo] + idx] = pkv & 0x7FFFFF;
  }
}

// ---------------- dense GEMM: G[n][M] = bf16((X[n][K] @ W[K][M]) * dinv[n]) ----------------
template <int K, int M, int R, int KS>
__global__ void __launch_bounds__(BLK) gemm_c2(const float* __restrict__ X,
                                               const float* __restrict__ W,
                                               const float* __restrict__ dinv,
                                               u16* __restrict__ G, int n) {
  constexpr int CP = M / 2;          // col-pairs
  constexpr int GROUPS = BLK / CP;   // row groups
  constexpr int ROWS = GROUPS * R;
  __shared__ float xs[ROWS][K + 4];
  __shared__ float ws[KS][M];
  const int tid = threadIdx.x;
  const int row0 = blockIdx.x * ROWS;
  const int cp = tid % CP;
  const int grp = tid / CP;

  constexpr int XTOT = ROWS * K;
  for (int i = tid * 4; i < XTOT; i += BLK * 4) {
    int r = i / K, c = i % K;
    int gr = row0 + r;
    if (gr >= n) gr = n - 1;  // clamp (stores guarded)
    *(float4*)&xs[r][c] = *(const float4*)&X[(size_t)gr * K + c];
  }

  float acc[R][2];
#pragma unroll
  for (int r = 0; r < R; r++) { acc[r][0] = 0.f; acc[r][1] = 0.f; }

  for (int ks = 0; ks < K; ks += KS) {
    __syncthreads();  // covers xs stage (iter 0) and ws re-stage
    for (int i = tid * 4; i < KS * M; i += BLK * 4)
      *(float4*)&((float*)ws)[i] = *(const float4*)&W[(size_t)ks * M + i];
    __syncthreads();
    for (int k4 = 0; k4 < KS; k4 += 4) {
      const float2 wA = *(const float2*)&ws[k4 + 0][cp * 2];
      const float2 wB = *(const float2*)&ws[k4 + 1][cp * 2];
      const float2 wC = *(const float2*)&ws[k4 + 2][cp * 2];
      const float2 wD = *(const float2*)&ws[k4 + 3][cp * 2];
#pragma unroll
      for (int r = 0; r < R; r++) {
        const float4 xa = *(const float4*)&xs[grp * R + r][ks + k4];
        acc[r][0] += xa.x * wA.x + xa.y * wB.x + xa.z * wC.x + xa.w * wD.x;
        acc[r][1] += xa.x * wA.y + xa.y * wB.y + xa.z * wC.y + xa.w * wD.y;
      }
    }
  }

#pragma unroll
  for (int r = 0; r < R; r++) {
    int gr = row0 + grp * R + r;
    if (gr < n) {
      float s = dinv[gr];
      unsigned pack = (unsigned)f2bf(acc[r][0] * s) | ((unsigned)f2bf(acc[r][1] * s) << 16);
      *(unsigned*)&G[(size_t)gr * M + cp * 2] = pack;
    }
  }
}

// ---------------- aggregation ----------------
// gs (bf16, N+1 rows; row n is all-zero pad) holds (X@W)*dinv[row].
// out[i] = relu(dinv[i]*(gs[i] + sum_s gs[s]) + b)

// layer 1: 64 ch. Lane q=lane>>4 handles neighbor j+q, cs=lane&15 handles
// channels 4cs..4cs+3 (uint2 = 4 bf16). 8 neighbors per iter (2 gathers in
// flight). OOB slots gather the zero row -> no masked adds.
__global__ void __launch_bounds__(BLK) agg1_kernel(const u16* __restrict__ gs,
                                                   const int* __restrict__ row_ptr,
                                                   const int* __restrict__ col,
                                                   const float* __restrict__ dinv,
                                                   const float* __restrict__ bias,
                                                   float* __restrict__ out, int n) {
  int node = (blockIdx.x * BLK + threadIdx.x) >> 6;
  int lane = threadIdx.x & 63;
  if (node >= n) return;
  const int q = lane >> 4;
  const int cs = lane & 15;
  int beg = row_ptr[node], end = row_ptr[node + 1];
  float a0, a1, a2, a3;
  {  // self-loop slice (quarter 0 only; others start at 0)
    uint2 u = *(const uint2*)&gs[(size_t)node * 64 + cs * 4];
    float m = (q == 0) ? 1.f : 0.f;
    a0 = m * bf_lo(u.x); a1 = m * bf_hi(u.x);
    a2 = m * bf_lo(u.y); a3 = m * bf_hi(u.y);
  }
  for (int j = beg; j < end; j += 8) {
    int jj0 = j + q, jj1 = j + 4 + q;
    int s0 = (jj0 < end) ? col[jj0] : n;  // n = zero row
    int s1 = (jj1 < end) ? col[jj1] : n;
    uint2 u0 = *(const uint2*)&gs[(size_t)s0 * 64 + cs * 4];
    uint2 u1 = *(const uint2*)&gs[(size_t)s1 * 64 + cs * 4];
    a0 += bf_lo(u0.x); a1 += bf_hi(u0.x); a2 += bf_lo(u0.y); a3 += bf_hi(u0.y);
    a0 += bf_lo(u1.x); a1 += bf_hi(u1.x); a2 += bf_lo(u1.y); a3 += bf_hi(u1.y);
  }
  // reduce quarters
  a0 += __shfl_xor(a0, 16); a1 += __shfl_xor(a1, 16);
  a2 += __shfl_xor(a2, 16); a3 += __shfl_xor(a3, 16);
  a0 += __shfl_xor(a0, 32); a1 += __shfl_xor(a1, 32);
  a2 += __shfl_xor(a2, 32); a3 += __shfl_xor(a3, 32);
  if (q == 0) {
    float di = dinv[node];
    float4 bv = *(const float4*)&bias[cs * 4];
    float4 o;
    o.x = a0 * di + bv.x; o.y = a1 * di + bv.y;
    o.z = a2 * di + bv.z; o.w = a3 * di + bv.w;
    o.x = o.x > 0.f ? o.x : 0.f;
    o.y = o.y > 0.f ? o.y : 0.f;
    o.z = o.z > 0.f ? o.z : 0.f;
    o.w = o.w > 0.f ? o.w : 0.f;
    *(float4*)&out[(size_t)node * 64 + cs * 4] = o;
  }
}

// layer 2: 32 ch. q=lane>>3 (8 neighbor slots), cs=lane&7 (4 ch each).
__global__ void __launch_bounds__(BLK) agg2_kernel(const u16* __restrict__ gs,
                                                   const int* __restrict__ row_ptr,
                                                   const int* __restrict__ col,
                                                   const float* __restrict__ dinv,
                                                   const float* __restrict__ bias,
                                                   float* __restrict__ out, int n) {
  int node = (blockIdx.x * BLK + threadIdx.x) >> 6;
  int lane = threadIdx.x & 63;
  if (node >= n) return;
  const int q = lane >> 3;
  const int cs = lane & 7;
  int beg = row_ptr[node], end = row_ptr[node + 1];
  float a0, a1, a2, a3;
  {
    uint2 u = *(const uint2*)&gs[(size_t)node * 32 + cs * 4];
    float m = (q == 0) ? 1.f : 0.f;
    a0 = m * bf_lo(u.x); a1 = m * bf_hi(u.x);
    a2 = m * bf_lo(u.y); a3 = m * bf_hi(u.y);
  }
  for (int j = beg; j < end; j += 8) {
    int jj = j + q;
    int s = (jj < end) ? col[jj] : n;  // n = zero row
    uint2 u = *(const uint2*)&gs[(size_t)s * 32 + cs * 4];
    a0 += bf_lo(u.x); a1 += bf_hi(u.x); a2 += bf_lo(u.y); a3 += bf_hi(u.y);
  }
  a0 += __shfl_xor(a0, 8);  a1 += __shfl_xor(a1, 8);
  a2 += __shfl_xor(a2, 8);  a3 += __shfl_xor(a3, 8);
  a0 += __shfl_xor(a0, 16); a1 += __shfl_xor(a1, 16);
  a2 += __shfl_xor(a2, 16); a3 += __shfl_xor(a3, 16);
  a0 += __shfl_xor(a0, 32); a1 += __shfl_xor(a1, 32);
  a2 += __shfl_xor(a2, 32); a3 += __shfl_xor(a3, 32);
  if (q == 0) {
    float di = dinv[node];
    float4 bv = *(const float4*)&bias[cs * 4];
    float4 o;
    o.x = a0 * di + bv.x; o.y = a1 * di + bv.y;
    o.z = a2 * di + bv.z; o.w = a3 * di + bv.w;
    o.x = o.x > 0.f ? o.x : 0.f;
    o.y = o.y > 0.f ? o.y : 0.f;
    o.z = o.z > 0.f ? o.z : 0.f;
    o.w = o.w > 0.f ? o.w : 0.f;
    *(float4*)&out[(size_t)node * 32 + cs * 4] = o;
  }
}

// ---------------- launcher ----------------

extern "C" void kernel_launch(void* const* d_in, const int* in_sizes, int n_in,
                              void* d_out, int out_size, void* d_ws, size_t ws_size,
                              hipStream_t stream) {
  const float* x = (const float*)d_in[0];
  const int* ei = (const int*)d_in[1];
  const float* W1 = (const float*)d_in[2];
  const float* b1 = (const float*)d_in[3];
  const float* W2 = (const float*)d_in[4];
  const float* b2 = (const float*)d_in[5];

  const int N = in_sizes[0] / 128;
  const int E = in_sizes[1] / 2;
  const int* src = ei;
  const int* dst = ei + E;
  const int nb = (N + BSPAN - 1) >> BSHIFT;  // # coarse buckets (196 @ N=100K)

  char* p = (char*)d_ws;
  auto take = [&](size_t bytes) -> char* {
    char* q = p;
    p += (bytes + 255) & ~(size_t)255;
    return q;
  };
  int* bins = (int*)take((size_t)NB_MAX * CAP * 4);
  int* tail = (int*)take(NB_MAX * 4);
  int* bbase = (int*)take(NB_MAX * 4);
  int* row_ptr = (int*)take((size_t)(N + 1) * 4);
  int* col = (int*)take((size_t)E * 4);
  float* dinv = (float*)take((size_t)N * 4);
  u16* g1 = (u16*)take((size_t)(N + 1) * 64 * 2);  // +1 zero row
  float* h = (float*)take((size_t)N * 64 * 4);
  u16* g2 = (u16*)take((size_t)(N + 1) * 32 * 2);  // +1 zero row

  hipMemsetAsync(tail, 0, NB_MAX * 4, stream);
  hipMemsetAsync(g1 + (size_t)N * 64, 0, 64 * 2, stream);  // zero pad row
  hipMemsetAsync(g2 + (size_t)N * 32, 0, 32 * 2, stream);  // zero pad row

  binpass<<<(E + EPBB - 1) / EPBB, BLK, 0, stream>>>(src, dst, E, bins, tail);
  scan256<<<1, BLK, 0, stream>>>(tail, bbase, row_ptr, N, E);
  bucket_sort<<<nb, BLK, 0, stream>>>(bins, tail, bbase, row_ptr, col, dinv, N);

  gemm_c2<128, 64, 8, 64><<<(N + 63) / 64, BLK, 0, stream>>>(x, W1, dinv, g1, N);
  agg1_kernel<<<(N + 3) / 4, BLK, 0, stream>>>(g1, row_ptr, col, dinv, b1, h, N);
  gemm_c2<64, 32, 4, 64><<<(N + 63) / 64, BLK, 0, stream>>>(h, W2, dinv, g2, N);
  agg2_kernel<<<(N + 3) / 4, BLK, 0, stream>>>(g2, row_ptr, col, dinv, b2, (float*)d_out, N);
}

// Round 11
// 179.790 us; speedup vs baseline: 2.2345x; 1.1918x over previous
//
#include <hip/hip_runtime.h>
#include <math.h>

constexpr int BLK = 256;
constexpr int NB_MAX = 256;      // max coarse buckets (supports N <= 131072)
constexpr int BSHIFT = 9;        // 512 nodes per bucket
constexpr int BSPAN = 1 << BSHIFT;
constexpr int CAP = 10240;       // per-bucket bin capacity (mean 8192 @ E=1.6M)
constexpr int EPT2 = 16;         // edges per thread in binpass
constexpr int EPBB = BLK * EPT2; // 4096 edges per block

typedef unsigned short u16;
typedef __attribute__((ext_vector_type(8))) short short8_t;
typedef __attribute__((ext_vector_type(4))) float f32x4;

// ---- bf16 helpers ----
__device__ __forceinline__ u16 f2bf(float f) {
  union { float f; unsigned int i; } v;
  v.f = f;
  unsigned int r = v.i + 0x7FFF + ((v.i >> 16) & 1);  // RNE
  return (u16)(r >> 16);
}
__device__ __forceinline__ float bf_lo(unsigned u) {
  union { unsigned int i; float f; } v;
  v.i = u << 16;
  return v.f;
}
__device__ __forceinline__ float bf_hi(unsigned u) {
  union { unsigned int i; float f; } v;
  v.i = u & 0xFFFF0000u;
  return v.f;
}

// ---------------- pass 1: coarse binning into block-private chunks ----------------
__global__ void __launch_bounds__(BLK) binpass(const int* __restrict__ src,
                                               const int* __restrict__ dst,
                                               int e, int* __restrict__ bins,
                                               int* __restrict__ tail) {
  __shared__ int lcnt[NB_MAX], gbase[NB_MAX], lcur[NB_MAX];
  const int tid = threadIdx.x;
  lcnt[tid] = 0;
  lcur[tid] = 0;
  __syncthreads();
  const int i0 = blockIdx.x * EPBB;
  int bb[EPT2], pk[EPT2];
#pragma unroll
  for (int k = 0; k < EPT2; k++) {
    int i = i0 + k * BLK + tid;
    if (i < e) {
      int d = dst[i], s = src[i];
      bb[k] = d >> BSHIFT;
      pk[k] = ((d & (BSPAN - 1)) << 23) | s;   // src < 2^23, dlo < 2^9
      atomicAdd(&lcnt[bb[k]], 1);
    } else {
      bb[k] = -1;
    }
  }
  __syncthreads();
  gbase[tid] = atomicAdd(&tail[tid], lcnt[tid]);  // reserve contiguous chunk per bucket
  __syncthreads();
#pragma unroll
  for (int k = 0; k < EPT2; k++) {
    if (bb[k] >= 0) {
      int idx = atomicAdd(&lcur[bb[k]], 1);
      bins[bb[k] * CAP + gbase[bb[k]] + idx] = pk[k];
    }
  }
}

// ---------------- pass 2: exclusive scan of bucket totals ----------------
__global__ void __launch_bounds__(BLK) scan256(const int* __restrict__ tail,
                                               int* __restrict__ bbase,
                                               int* __restrict__ row_ptr,
                                               int n, int e) {
  __shared__ int sd[BLK];
  int v = tail[threadIdx.x];
  sd[threadIdx.x] = v;
  __syncthreads();
  for (int off = 1; off < BLK; off <<= 1) {
    int t = (threadIdx.x >= off) ? sd[threadIdx.x - off] : 0;
    __syncthreads();
    sd[threadIdx.x] += t;
    __syncthreads();
  }
  bbase[threadIdx.x] = sd[threadIdx.x] - v;
  if (threadIdx.x == 0) row_ptr[n] = e;
}

// ---------------- pass 3: per-bucket counting sort (block-private col region) ----------------
__global__ void __launch_bounds__(BLK) bucket_sort(const int* __restrict__ bins,
                                                   const int* __restrict__ tail,
                                                   const int* __restrict__ bbase,
                                                   int* __restrict__ row_ptr,
                                                   int* __restrict__ col,
                                                   float* __restrict__ dinv, int n) {
  __shared__ int hist[BSPAN], lpre[BSPAN], lcur[BSPAN], sd[BLK];
  const int b = blockIdx.x, tid = threadIdx.x;
  const int cnt = tail[b];
  const int base = bbase[b];
  const int node0 = b << BSHIFT;
  const int nNodes = min(BSPAN, n - node0);
  const int* bin = bins + (size_t)b * CAP;

  hist[tid] = 0; hist[tid + BLK] = 0;
  lcur[tid] = 0; lcur[tid + BLK] = 0;
  __syncthreads();
  for (int j = tid; j < cnt; j += BLK) atomicAdd(&hist[(unsigned)bin[j] >> 23], 1);
  __syncthreads();
  // exclusive scan over 512 counters (2 per thread)
  int v0 = hist[2 * tid], v1 = hist[2 * tid + 1], ts = v0 + v1;
  sd[tid] = ts;
  __syncthreads();
  for (int off = 1; off < BLK; off <<= 1) {
    int t = (tid >= off) ? sd[tid - off] : 0;
    __syncthreads();
    sd[tid] += t;
    __syncthreads();
  }
  int ex = sd[tid] - ts;
  lpre[2 * tid] = ex;
  lpre[2 * tid + 1] = ex + v0;
  __syncthreads();
  for (int d = tid; d < nNodes; d += BLK) {
    row_ptr[node0 + d] = base + lpre[d];
    dinv[node0 + d] = rsqrtf((float)hist[d] + 1.0f);
  }
  for (int j = tid; j < cnt; j += BLK) {
    int pkv = bin[j];
    int dlo = (unsigned)pkv >> 23;
    int idx = atomicAdd(&lcur[dlo], 1);
    col[base + lpre[dlo] + idx] = pkv & 0x7FFFFF;
  }
}

// ---------------- MFMA GEMM via split-bf16: G = bf16((X @ W) * dinv) ----------------
// D = A*B + C with A = X rows (fp32 -> hi/lo bf16 in regs), B = W (staged
// transposed + split in LDS). 3 MFMA per tile (hi*hi + lo*hi + hi*lo); dropped
// lo*lo ~ 2^-17 relative -> fp32-grade accuracy. 256 thr = 4 waves x 16 rows.
// Layouts (m89-verified): A: row=lane&15, k=(lane>>4)*8+j; B: col=lane&15,
// k=(lane>>4)*8+j; C/D: col=lane&15, row=(lane>>4)*4+reg.
template <int K, int M>
__global__ void __launch_bounds__(BLK) gemm_mfma(const float* __restrict__ X,
                                                 const float* __restrict__ W,
                                                 const float* __restrict__ dinv,
                                                 u16* __restrict__ G, int n) {
  constexpr int KC = K / 32;   // K-chunks
  constexpr int CT = M / 16;   // 16-col tiles
  constexpr int PADK = K + 8;  // row stride 272B (K=128): 2-way bank alias = free
  __shared__ u16 wt_hi[M][PADK];
  __shared__ u16 wt_lo[M][PADK];
  const int tid = threadIdx.x;
  const int lane = tid & 63;
  const int wv = tid >> 6;

  // stage W transposed + hi/lo split (one-time; reads coalesced)
  for (int i = tid; i < K * M; i += BLK) {
    int k = i / M, m = i % M;
    float w = W[i];
    unsigned wb = __float_as_uint(w);
    wt_hi[m][k] = (u16)(wb >> 16);                       // truncation hi
    wt_lo[m][k] = f2bf(w - __uint_as_float(wb & 0xFFFF0000u));
  }
  __syncthreads();

  const int r16 = lane & 15;
  const int oct = lane >> 4;
  int rowA = blockIdx.x * 64 + wv * 16 + r16;
  if (rowA >= n) rowA = n - 1;  // clamp (stores guarded)

  f32x4 acc[CT];
#pragma unroll
  for (int ct = 0; ct < CT; ct++) acc[ct] = (f32x4){0.f, 0.f, 0.f, 0.f};

#pragma unroll
  for (int kc = 0; kc < KC; kc++) {
    // A fragment: 8 fp32 from global, split hi/lo in regs
    const float* xp = &X[(size_t)rowA * K + kc * 32 + oct * 8];
    float4 v0 = *(const float4*)xp;
    float4 v1 = *(const float4*)(xp + 4);
    float vv[8] = {v0.x, v0.y, v0.z, v0.w, v1.x, v1.y, v1.z, v1.w};
    short8_t ahi, alo;
#pragma unroll
    for (int j = 0; j < 8; j++) {
      unsigned xb = __float_as_uint(vv[j]);
      ahi[j] = (short)(xb >> 16);  // truncation hi
      alo[j] = (short)f2bf(vv[j] - __uint_as_float(xb & 0xFFFF0000u));
    }
#pragma unroll
    for (int ct = 0; ct < CT; ct++) {
      short8_t bhi = *(const short8_t*)&wt_hi[ct * 16 + r16][kc * 32 + oct * 8];
      short8_t blo = *(const short8_t*)&wt_lo[ct * 16 + r16][kc * 32 + oct * 8];
      acc[ct] = __builtin_amdgcn_mfma_f32_16x16x32_bf16(ahi, bhi, acc[ct], 0, 0, 0);
      acc[ct] = __builtin_amdgcn_mfma_f32_16x16x32_bf16(alo, bhi, acc[ct], 0, 0, 0);
      acc[ct] = __builtin_amdgcn_mfma_f32_16x16x32_bf16(ahi, blo, acc[ct], 0, 0, 0);
    }
  }

  // epilogue: C row = oct*4 + reg, col = ct*16 + r16
  const int rbase = blockIdx.x * 64 + wv * 16 + oct * 4;
  float dv[4];
#pragma unroll
  for (int r = 0; r < 4; r++) {
    int gr = rbase + r;
    dv[r] = (gr < n) ? dinv[gr] : 0.f;
  }
#pragma unroll
  for (int ct = 0; ct < CT; ct++) {
#pragma unroll
    for (int r = 0; r < 4; r++) {
      int gr = rbase + r;
      if (gr < n) G[(size_t)gr * M + ct * 16 + r16] = f2bf(acc[ct][r] * dv[r]);
    }
  }
}

// ---------------- aggregation ----------------
// gs (bf16, N+1 rows; row n is all-zero pad) holds (X@W)*dinv[row].
// out[i] = relu(dinv[i]*(gs[i] + sum_s gs[s]) + b)

__global__ void __launch_bounds__(BLK) agg1_kernel(const u16* __restrict__ gs,
                                                   const int* __restrict__ row_ptr,
                                                   const int* __restrict__ col,
                                                   const float* __restrict__ dinv,
                                                   const float* __restrict__ bias,
                                                   float* __restrict__ out, int n) {
  int node = (blockIdx.x * BLK + threadIdx.x) >> 6;
  int lane = threadIdx.x & 63;
  if (node >= n) return;
  const int q = lane >> 4;
  const int cs = lane & 15;
  int beg = row_ptr[node], end = row_ptr[node + 1];
  float a0, a1, a2, a3;
  {  // self-loop slice (quarter 0 only; others start at 0)
    uint2 u = *(const uint2*)&gs[(size_t)node * 64 + cs * 4];
    float m = (q == 0) ? 1.f : 0.f;
    a0 = m * bf_lo(u.x); a1 = m * bf_hi(u.x);
    a2 = m * bf_lo(u.y); a3 = m * bf_hi(u.y);
  }
  for (int j = beg; j < end; j += 8) {
    int jj0 = j + q, jj1 = j + 4 + q;
    int s0 = (jj0 < end) ? col[jj0] : n;  // n = zero row
    int s1 = (jj1 < end) ? col[jj1] : n;
    uint2 u0 = *(const uint2*)&gs[(size_t)s0 * 64 + cs * 4];
    uint2 u1 = *(const uint2*)&gs[(size_t)s1 * 64 + cs * 4];
    a0 += bf_lo(u0.x); a1 += bf_hi(u0.x); a2 += bf_lo(u0.y); a3 += bf_hi(u0.y);
    a0 += bf_lo(u1.x); a1 += bf_hi(u1.x); a2 += bf_lo(u1.y); a3 += bf_hi(u1.y);
  }
  // reduce quarters
  a0 += __shfl_xor(a0, 16); a1 += __shfl_xor(a1, 16);
  a2 += __shfl_xor(a2, 16); a3 += __shfl_xor(a3, 16);
  a0 += __shfl_xor(a0, 32); a1 += __shfl_xor(a1, 32);
  a2 += __shfl_xor(a2, 32); a3 += __shfl_xor(a3, 32);
  if (q == 0) {
    float di = dinv[node];
    float4 bv = *(const float4*)&bias[cs * 4];
    float4 o;
    o.x = a0 * di + bv.x; o.y = a1 * di + bv.y;
    o.z = a2 * di + bv.z; o.w = a3 * di + bv.w;
    o.x = o.x > 0.f ? o.x : 0.f;
    o.y = o.y > 0.f ? o.y : 0.f;
    o.z = o.z > 0.f ? o.z : 0.f;
    o.w = o.w > 0.f ? o.w : 0.f;
    *(float4*)&out[(size_t)node * 64 + cs * 4] = o;
  }
}

__global__ void __launch_bounds__(BLK) agg2_kernel(const u16* __restrict__ gs,
                                                   const int* __restrict__ row_ptr,
                                                   const int* __restrict__ col,
                                                   const float* __restrict__ dinv,
                                                   const float* __restrict__ bias,
                                                   float* __restrict__ out, int n) {
  int node = (blockIdx.x * BLK + threadIdx.x) >> 6;
  int lane = threadIdx.x & 63;
  if (node >= n) return;
  const int q = lane >> 3;
  const int cs = lane & 7;
  int beg = row_ptr[node], end = row_ptr[node + 1];
  float a0, a1, a2, a3;
  {
    uint2 u = *(const uint2*)&gs[(size_t)node * 32 + cs * 4];
    float m = (q == 0) ? 1.f : 0.f;
    a0 = m * bf_lo(u.x); a1 = m * bf_hi(u.x);
    a2 = m * bf_lo(u.y); a3 = m * bf_hi(u.y);
  }
  for (int j = beg; j < end; j += 8) {
    int jj = j + q;
    int s = (jj < end) ? col[jj] : n;  // n = zero row
    uint2 u = *(const uint2*)&gs[(size_t)s * 32 + cs * 4];
    a0 += bf_lo(u.x); a1 += bf_hi(u.x); a2 += bf_lo(u.y); a3 += bf_hi(u.y);
  }
  a0 += __shfl_xor(a0, 8);  a1 += __shfl_xor(a1, 8);
  a2 += __shfl_xor(a2, 8);  a3 += __shfl_xor(a3, 8);
  a0 += __shfl_xor(a0, 16); a1 += __shfl_xor(a1, 16);
  a2 += __shfl_xor(a2, 16); a3 += __shfl_xor(a3, 16);
  a0 += __shfl_xor(a0, 32); a1 += __shfl_xor(a1, 32);
  a2 += __shfl_xor(a2, 32); a3 += __shfl_xor(a3, 32);
  if (q == 0) {
    float di = dinv[node];
    float4 bv = *(const float4*)&bias[cs * 4];
    float4 o;
    o.x = a0 * di + bv.x; o.y = a1 * di + bv.y;
    o.z = a2 * di + bv.z; o.w = a3 * di + bv.w;
    o.x = o.x > 0.f ? o.x : 0.f;
    o.y = o.y > 0.f ? o.y : 0.f;
    o.z = o.z > 0.f ? o.z : 0.f;
    o.w = o.w > 0.f ? o.w : 0.f;
    *(float4*)&out[(size_t)node * 32 + cs * 4] = o;
  }
}

// ---------------- launcher ----------------

extern "C" void kernel_launch(void* const* d_in, const int* in_sizes, int n_in,
                              void* d_out, int out_size, void* d_ws, size_t ws_size,
                              hipStream_t stream) {
  const float* x = (const float*)d_in[0];
  const int* ei = (const int*)d_in[1];
  const float* W1 = (const float*)d_in[2];
  const float* b1 = (const float*)d_in[3];
  const float* W2 = (const float*)d_in[4];
  const float* b2 = (const float*)d_in[5];

  const int N = in_sizes[0] / 128;
  const int E = in_sizes[1] / 2;
  const int* src = ei;
  const int* dst = ei + E;
  const int nb = (N + BSPAN - 1) >> BSHIFT;  // # coarse buckets (196 @ N=100K)

  char* p = (char*)d_ws;
  auto take = [&](size_t bytes) -> char* {
    char* q = p;
    p += (bytes + 255) & ~(size_t)255;
    return q;
  };
  int* bins = (int*)take((size_t)NB_MAX * CAP * 4);
  int* tail = (int*)take(NB_MAX * 4);
  int* bbase = (int*)take(NB_MAX * 4);
  int* row_ptr = (int*)take((size_t)(N + 1) * 4);
  int* col = (int*)take((size_t)E * 4);
  float* dinv = (float*)take((size_t)N * 4);
  u16* g1 = (u16*)take((size_t)(N + 1) * 64 * 2);  // +1 zero row
  float* h = (float*)take((size_t)N * 64 * 4);
  u16* g2 = (u16*)take((size_t)(N + 1) * 32 * 2);  // +1 zero row

  hipMemsetAsync(tail, 0, NB_MAX * 4, stream);
  hipMemsetAsync(g1 + (size_t)N * 64, 0, 64 * 2, stream);  // zero pad row
  hipMemsetAsync(g2 + (size_t)N * 32, 0, 32 * 2, stream);  // zero pad row

  binpass<<<(E + EPBB - 1) / EPBB, BLK, 0, stream>>>(src, dst, E, bins, tail);
  scan256<<<1, BLK, 0, stream>>>(tail, bbase, row_ptr, N, E);
  bucket_sort<<<nb, BLK, 0, stream>>>(bins, tail, bbase, row_ptr, col, dinv, N);

  gemm_mfma<128, 64><<<(N + 63) / 64, BLK, 0, stream>>>(x, W1, dinv, g1, N);
  agg1_kernel<<<(N + 3) / 4, BLK, 0, stream>>>(g1, row_ptr, col, dinv, b1, h, N);
  gemm_mfma<64, 32><<<(N + 63) / 64, BLK, 0, stream>>>(h, W2, dinv, g2, N);
  agg2_kernel<<<(N + 3) / 4, BLK, 0, stream>>>(g2, row_ptr, col, dinv, b2, (float*)d_out, N);
}

// Round 12
// 170.837 us; speedup vs baseline: 2.3516x; 1.0524x over previous
//
#include <hip/hip_runtime.h>
#include <math.h>

constexpr int BLK = 256;
constexpr int NB_MAX = 256;      // max coarse buckets (supports N <= 131072)
constexpr int BSHIFT = 9;        // 512 nodes per bucket
constexpr int BSPAN = 1 << BSHIFT;
constexpr int CAP = 10240;       // per-bucket bin capacity (mean 8192 @ E=1.6M, +22 sigma)
constexpr int CAP2 = 12800;      // per-bucket padded col capacity (mean 9984, +31 sigma)
constexpr int EPT2 = 16;         // edges per thread in binpass
constexpr int EPBB = BLK * EPT2; // 4096 edges per block

typedef unsigned short u16;
typedef __attribute__((ext_vector_type(8))) short short8_t;
typedef __attribute__((ext_vector_type(4))) float f32x4;

// ---- bf16 helpers ----
__device__ __forceinline__ u16 f2bf(float f) {
  union { float f; unsigned int i; } v;
  v.f = f;
  unsigned int r = v.i + 0x7FFF + ((v.i >> 16) & 1);  // RNE
  return (u16)(r >> 16);
}
__device__ __forceinline__ float bf_lo(unsigned u) {
  union { unsigned int i; float f; } v;
  v.i = u << 16;
  return v.f;
}
__device__ __forceinline__ float bf_hi(unsigned u) {
  union { unsigned int i; float f; } v;
  v.i = u & 0xFFFF0000u;
  return v.f;
}

// ---------------- pass 1: coarse binning into block-private chunks ----------------
__global__ void __launch_bounds__(BLK) binpass(const int* __restrict__ src,
                                               const int* __restrict__ dst,
                                               int e, int* __restrict__ bins,
                                               int* __restrict__ tail) {
  __shared__ int lcnt[NB_MAX], gbase[NB_MAX], lcur[NB_MAX];
  const int tid = threadIdx.x;
  lcnt[tid] = 0;
  lcur[tid] = 0;
  __syncthreads();
  const int i0 = blockIdx.x * EPBB;
  int bb[EPT2], pk[EPT2];
#pragma unroll
  for (int k = 0; k < EPT2; k++) {
    int i = i0 + k * BLK + tid;
    if (i < e) {
      int d = dst[i], s = src[i];
      bb[k] = d >> BSHIFT;
      pk[k] = ((d & (BSPAN - 1)) << 23) | s;   // src < 2^23, dlo < 2^9
      atomicAdd(&lcnt[bb[k]], 1);
    } else {
      bb[k] = -1;
    }
  }
  __syncthreads();
  gbase[tid] = atomicAdd(&tail[tid], lcnt[tid]);  // reserve contiguous chunk per bucket
  __syncthreads();
#pragma unroll
  for (int k = 0; k < EPT2; k++) {
    if (bb[k] >= 0) {
      int idx = atomicAdd(&lcur[bb[k]], 1);
      bins[bb[k] * CAP + gbase[bb[k]] + idx] = pk[k];
    }
  }
}

// ---------------- pass 2: per-bucket counting sort into FIXED col region ----------------
// Bucket b owns col[b*CAP2 .. b*CAP2+CAP2). Per-node segments padded to mult-of-8
// with pad entries = n (zero row). wdesc[node] = (beg<<10) | ceil(deg/8).
__global__ void __launch_bounds__(BLK) bucket_sort(const int* __restrict__ bins,
                                                   const int* __restrict__ tail,
                                                   unsigned* __restrict__ wdesc,
                                                   int* __restrict__ col,
                                                   float* __restrict__ dinv, int n) {
  __shared__ int hist[BSPAN], lpre[BSPAN], lcur[BSPAN], sd[BLK];
  const int b = blockIdx.x, tid = threadIdx.x;
  const int cnt = tail[b];
  const int base = b * CAP2;
  const int node0 = b << BSHIFT;
  const int nNodes = min(BSPAN, n - node0);
  const int* bin = bins + (size_t)b * CAP;

  hist[tid] = 0; hist[tid + BLK] = 0;
  lcur[tid] = 0; lcur[tid + BLK] = 0;
  __syncthreads();
  for (int j = tid; j < cnt; j += BLK) atomicAdd(&hist[(unsigned)bin[j] >> 23], 1);
  __syncthreads();
  // exclusive scan over PADDED counts (2 per thread)
  int h0 = hist[2 * tid], h1 = hist[2 * tid + 1];
  int p0 = (h0 + 7) & ~7, p1 = (h1 + 7) & ~7;
  int ts = p0 + p1;
  sd[tid] = ts;
  __syncthreads();
  for (int off = 1; off < BLK; off <<= 1) {
    int t = (tid >= off) ? sd[tid - off] : 0;
    __syncthreads();
    sd[tid] += t;
    __syncthreads();
  }
  int ex = sd[tid] - ts;
  lpre[2 * tid] = ex;
  lpre[2 * tid + 1] = ex + p0;
  __syncthreads();
  for (int d = tid; d < nNodes; d += BLK) {
    int hd = hist[d];
    int begd = base + lpre[d];
    wdesc[node0 + d] = ((unsigned)begd << 10) | (unsigned)((hd + 7) >> 3);
    dinv[node0 + d] = rsqrtf((float)hd + 1.0f);
    int pe = (hd + 7) & ~7;
    for (int t = hd; t < pe; t++) col[begd + t] = n;  // pad -> zero row
  }
  __syncthreads();
  for (int j = tid; j < cnt; j += BLK) {
    int pkv = bin[j];
    int dlo = (unsigned)pkv >> 23;
    int idx = atomicAdd(&lcur[dlo], 1);
    col[base + lpre[dlo] + idx] = pkv & 0x7FFFFF;
  }
}

// ---------------- MFMA GEMM via split-bf16: G = bf16((X @ W) * dinv) ----------------
// 3 MFMA per tile (hi*hi + lo*hi + hi*lo); fp32-grade accuracy. Block 0 also
// zeroes the pad row G[n][*] (read by agg for padded slots).
template <int K, int M>
__global__ void __launch_bounds__(BLK) gemm_mfma(const float* __restrict__ X,
                                                 const float* __restrict__ W,
                                                 const float* __restrict__ dinv,
                                                 u16* __restrict__ G, int n) {
  constexpr int KC = K / 32;   // K-chunks
  constexpr int CT = M / 16;   // 16-col tiles
  constexpr int PADK = K + 8;  // row stride 272B (K=128): 2-way bank alias = free
  __shared__ u16 wt_hi[M][PADK];
  __shared__ u16 wt_lo[M][PADK];
  const int tid = threadIdx.x;
  const int lane = tid & 63;
  const int wv = tid >> 6;

  if (blockIdx.x == 0 && tid < M) G[(size_t)n * M + tid] = 0;  // zero pad row

  // stage W transposed + hi/lo split (one-time; reads coalesced)
  for (int i = tid; i < K * M; i += BLK) {
    int k = i / M, m = i % M;
    float w = W[i];
    unsigned wb = __float_as_uint(w);
    wt_hi[m][k] = (u16)(wb >> 16);                       // truncation hi
    wt_lo[m][k] = f2bf(w - __uint_as_float(wb & 0xFFFF0000u));
  }
  __syncthreads();

  const int r16 = lane & 15;
  const int oct = lane >> 4;
  int rowA = blockIdx.x * 64 + wv * 16 + r16;
  if (rowA >= n) rowA = n - 1;  // clamp (stores guarded)

  f32x4 acc[CT];
#pragma unroll
  for (int ct = 0; ct < CT; ct++) acc[ct] = (f32x4){0.f, 0.f, 0.f, 0.f};

#pragma unroll
  for (int kc = 0; kc < KC; kc++) {
    const float* xp = &X[(size_t)rowA * K + kc * 32 + oct * 8];
    float4 v0 = *(const float4*)xp;
    float4 v1 = *(const float4*)(xp + 4);
    float vv[8] = {v0.x, v0.y, v0.z, v0.w, v1.x, v1.y, v1.z, v1.w};
    short8_t ahi, alo;
#pragma unroll
    for (int j = 0; j < 8; j++) {
      unsigned xb = __float_as_uint(vv[j]);
      ahi[j] = (short)(xb >> 16);  // truncation hi
      alo[j] = (short)f2bf(vv[j] - __uint_as_float(xb & 0xFFFF0000u));
    }
#pragma unroll
    for (int ct = 0; ct < CT; ct++) {
      short8_t bhi = *(const short8_t*)&wt_hi[ct * 16 + r16][kc * 32 + oct * 8];
      short8_t blo = *(const short8_t*)&wt_lo[ct * 16 + r16][kc * 32 + oct * 8];
      acc[ct] = __builtin_amdgcn_mfma_f32_16x16x32_bf16(ahi, bhi, acc[ct], 0, 0, 0);
      acc[ct] = __builtin_amdgcn_mfma_f32_16x16x32_bf16(alo, bhi, acc[ct], 0, 0, 0);
      acc[ct] = __builtin_amdgcn_mfma_f32_16x16x32_bf16(ahi, blo, acc[ct], 0, 0, 0);
    }
  }

  // epilogue: C row = oct*4 + reg, col = ct*16 + r16
  const int rbase = blockIdx.x * 64 + wv * 16 + oct * 4;
  float dv[4];
#pragma unroll
  for (int r = 0; r < 4; r++) {
    int gr = rbase + r;
    dv[r] = (gr < n) ? dinv[gr] : 0.f;
  }
#pragma unroll
  for (int ct = 0; ct < CT; ct++) {
#pragma unroll
    for (int r = 0; r < 4; r++) {
      int gr = rbase + r;
      if (gr < n) G[(size_t)gr * M + ct * 16 + r16] = f2bf(acc[ct][r] * dv[r]);
    }
  }
}

// ---------------- aggregation ----------------
// gs (bf16, N+1 rows; row n zero). Segments padded to mult-of-8 with col=n ->
// loops are select-free. wdesc = (beg<<10)|nb8.

__global__ void __launch_bounds__(BLK) agg1_kernel(const u16* __restrict__ gs,
                                                   const unsigned* __restrict__ wdesc,
                                                   const int* __restrict__ col,
                                                   const float* __restrict__ dinv,
                                                   const float* __restrict__ bias,
                                                   float* __restrict__ out, int n) {
  int node = (blockIdx.x * BLK + threadIdx.x) >> 6;
  int lane = threadIdx.x & 63;
  if (node >= n) return;
  const int q = lane >> 4;
  const int cs = lane & 15;
  unsigned w = wdesc[node];
  int beg = (int)(w >> 10), nb = (int)(w & 1023);
  float a0, a1, a2, a3;
  {  // self-loop slice (quarter 0 only; others start at 0)
    uint2 u = *(const uint2*)&gs[(size_t)node * 64 + cs * 4];
    float m = (q == 0) ? 1.f : 0.f;
    a0 = m * bf_lo(u.x); a1 = m * bf_hi(u.x);
    a2 = m * bf_lo(u.y); a3 = m * bf_hi(u.y);
  }
  for (int i = 0; i < nb; i++) {
    int j = beg + i * 8;
    int s0 = col[j + q];
    int s1 = col[j + 4 + q];
    uint2 u0 = *(const uint2*)&gs[(size_t)s0 * 64 + cs * 4];
    uint2 u1 = *(const uint2*)&gs[(size_t)s1 * 64 + cs * 4];
    a0 += bf_lo(u0.x); a1 += bf_hi(u0.x); a2 += bf_lo(u0.y); a3 += bf_hi(u0.y);
    a0 += bf_lo(u1.x); a1 += bf_hi(u1.x); a2 += bf_lo(u1.y); a3 += bf_hi(u1.y);
  }
  a0 += __shfl_xor(a0, 16); a1 += __shfl_xor(a1, 16);
  a2 += __shfl_xor(a2, 16); a3 += __shfl_xor(a3, 16);
  a0 += __shfl_xor(a0, 32); a1 += __shfl_xor(a1, 32);
  a2 += __shfl_xor(a2, 32); a3 += __shfl_xor(a3, 32);
  if (q == 0) {
    float di = dinv[node];
    float4 bv = *(const float4*)&bias[cs * 4];
    float4 o;
    o.x = a0 * di + bv.x; o.y = a1 * di + bv.y;
    o.z = a2 * di + bv.z; o.w = a3 * di + bv.w;
    o.x = o.x > 0.f ? o.x : 0.f;
    o.y = o.y > 0.f ? o.y : 0.f;
    o.z = o.z > 0.f ? o.z : 0.f;
    o.w = o.w > 0.f ? o.w : 0.f;
    *(float4*)&out[(size_t)node * 64 + cs * 4] = o;
  }
}

__global__ void __launch_bounds__(BLK) agg2_kernel(const u16* __restrict__ gs,
                                                   const unsigned* __restrict__ wdesc,
                                                   const int* __restrict__ col,
                                                   const float* __restrict__ dinv,
                                                   const float* __restrict__ bias,
                                                   float* __restrict__ out, int n) {
  int node = (blockIdx.x * BLK + threadIdx.x) >> 6;
  int lane = threadIdx.x & 63;
  if (node >= n) return;
  const int q = lane >> 3;
  const int cs = lane & 7;
  unsigned w = wdesc[node];
  int beg = (int)(w >> 10), nb = (int)(w & 1023);
  float a0, a1, a2, a3;
  {
    uint2 u = *(const uint2*)&gs[(size_t)node * 32 + cs * 4];
    float m = (q == 0) ? 1.f : 0.f;
    a0 = m * bf_lo(u.x); a1 = m * bf_hi(u.x);
    a2 = m * bf_lo(u.y); a3 = m * bf_hi(u.y);
  }
  for (int i = 0; i < nb; i++) {
    int s = col[beg + i * 8 + q];
    uint2 u = *(const uint2*)&gs[(size_t)s * 32 + cs * 4];
    a0 += bf_lo(u.x); a1 += bf_hi(u.x); a2 += bf_lo(u.y); a3 += bf_hi(u.y);
  }
  a0 += __shfl_xor(a0, 8);  a1 += __shfl_xor(a1, 8);
  a2 += __shfl_xor(a2, 8);  a3 += __shfl_xor(a3, 8);
  a0 += __shfl_xor(a0, 16); a1 += __shfl_xor(a1, 16);
  a2 += __shfl_xor(a2, 16); a3 += __shfl_xor(a3, 16);
  a0 += __shfl_xor(a0, 32); a1 += __shfl_xor(a1, 32);
  a2 += __shfl_xor(a2, 32); a3 += __shfl_xor(a3, 32);
  if (q == 0) {
    float di = dinv[node];
    float4 bv = *(const float4*)&bias[cs * 4];
    float4 o;
    o.x = a0 * di + bv.x; o.y = a1 * di + bv.y;
    o.z = a2 * di + bv.z; o.w = a3 * di + bv.w;
    o.x = o.x > 0.f ? o.x : 0.f;
    o.y = o.y > 0.f ? o.y : 0.f;
    o.z = o.z > 0.f ? o.z : 0.f;
    o.w = o.w > 0.f ? o.w : 0.f;
    *(float4*)&out[(size_t)node * 32 + cs * 4] = o;
  }
}

// ---------------- launcher ----------------

extern "C" void kernel_launch(void* const* d_in, const int* in_sizes, int n_in,
                              void* d_out, int out_size, void* d_ws, size_t ws_size,
                              hipStream_t stream) {
  const float* x = (const float*)d_in[0];
  const int* ei = (const int*)d_in[1];
  const float* W1 = (const float*)d_in[2];
  const float* b1 = (const float*)d_in[3];
  const float* W2 = (const float*)d_in[4];
  const float* b2 = (const float*)d_in[5];

  const int N = in_sizes[0] / 128;
  const int E = in_sizes[1] / 2;
  const int* src = ei;
  const int* dst = ei + E;
  const int nb = (N + BSPAN - 1) >> BSHIFT;  // # coarse buckets (196 @ N=100K)

  char* p = (char*)d_ws;
  auto take = [&](size_t bytes) -> char* {
    char* q = p;
    p += (bytes + 255) & ~(size_t)255;
    return q;
  };
  int* bins = (int*)take((size_t)NB_MAX * CAP * 4);
  int* tail = (int*)take(NB_MAX * 4);
  unsigned* wdesc = (unsigned*)take((size_t)N * 4);
  int* col = (int*)take((size_t)nb * CAP2 * 4);
  float* dinv = (float*)take((size_t)N * 4);
  u16* g1 = (u16*)take((size_t)(N + 1) * 64 * 2);  // +1 zero row
  float* h = (float*)take((size_t)N * 64 * 4);
  u16* g2 = (u16*)take((size_t)(N + 1) * 32 * 2);  // +1 zero row

  hipMemsetAsync(tail, 0, NB_MAX * 4, stream);

  binpass<<<(E + EPBB - 1) / EPBB, BLK, 0, stream>>>(src, dst, E, bins, tail);
  bucket_sort<<<nb, BLK, 0, stream>>>(bins, tail, wdesc, col, dinv, N);

  gemm_mfma<128, 64><<<(N + 63) / 64, BLK, 0, stream>>>(x, W1, dinv, g1, N);
  agg1_kernel<<<(N + 3) / 4, BLK, 0, stream>>>(g1, wdesc, col, dinv, b1, h, N);
  gemm_mfma<64, 32><<<(N + 63) / 64, BLK, 0, stream>>>(h, W2, dinv, g2, N);
  agg2_kernel<<<(N + 3) / 4, BLK, 0, stream>>>(g2, wdesc, col, dinv, b2, (float*)d_out, N);
}

// Round 13
// 146.867 us; speedup vs baseline: 2.7354x; 1.1632x over previous
//
#include <hip/hip_runtime.h>
#include <math.h>

constexpr int BLK = 256;
constexpr int NB_MAX = 256;      // max coarse buckets (supports N <= 131072)
constexpr int BSHIFT = 9;        // 512 nodes per bucket
constexpr int BSPAN = 1 << BSHIFT;
constexpr int CAP = 10240;       // per-bucket bin capacity (mean 8192 @ E=1.6M, +22 sigma)
constexpr int CAP2 = 12800;      // per-bucket padded col capacity (mean 9984, +31 sigma)
constexpr int EPT2 = 16;         // edges per thread in binpass
constexpr int EPBB = BLK * EPT2; // 4096 edges per block

typedef unsigned short u16;
typedef __attribute__((ext_vector_type(8))) short short8_t;
typedef __attribute__((ext_vector_type(4))) float f32x4;

// ---- bf16 helpers ----
__device__ __forceinline__ u16 f2bf(float f) {
  union { float f; unsigned int i; } v;
  v.f = f;
  unsigned int r = v.i + 0x7FFF + ((v.i >> 16) & 1);  // RNE
  return (u16)(r >> 16);
}
__device__ __forceinline__ float bf_lo(unsigned u) {
  union { unsigned int i; float f; } v;
  v.i = u << 16;
  return v.f;
}
__device__ __forceinline__ float bf_hi(unsigned u) {
  union { unsigned int i; float f; } v;
  v.i = u & 0xFFFF0000u;
  return v.f;
}

// ---------------- pass 1: coarse binning into block-private chunks ----------------
__global__ void __launch_bounds__(BLK) binpass(const int* __restrict__ src,
                                               const int* __restrict__ dst,
                                               int e, int* __restrict__ bins,
                                               int* __restrict__ tail) {
  __shared__ int lcnt[NB_MAX], gbase[NB_MAX], lcur[NB_MAX];
  const int tid = threadIdx.x;
  lcnt[tid] = 0;
  lcur[tid] = 0;
  __syncthreads();
  const int i0 = blockIdx.x * EPBB;
  int bb[EPT2], pk[EPT2];
#pragma unroll
  for (int k = 0; k < EPT2; k++) {
    int i = i0 + k * BLK + tid;
    if (i < e) {
      int d = dst[i], s = src[i];
      bb[k] = d >> BSHIFT;
      pk[k] = ((d & (BSPAN - 1)) << 23) | s;   // src < 2^23, dlo < 2^9
      atomicAdd(&lcnt[bb[k]], 1);
    } else {
      bb[k] = -1;
    }
  }
  __syncthreads();
  gbase[tid] = atomicAdd(&tail[tid], lcnt[tid]);  // reserve contiguous chunk per bucket
  __syncthreads();
#pragma unroll
  for (int k = 0; k < EPT2; k++) {
    if (bb[k] >= 0) {
      int idx = atomicAdd(&lcur[bb[k]], 1);
      bins[bb[k] * CAP + gbase[bb[k]] + idx] = pk[k];
    }
  }
}

// ---------------- pass 2: per-bucket counting sort into FIXED col region ----------------
// Bucket b owns col[b*CAP2 .. b*CAP2+CAP2). Per-node segments padded to mult-of-8
// with pad entries = n (zero row). wdesc[node] = (beg<<10) | ceil(deg/8).
__global__ void __launch_bounds__(BLK) bucket_sort(const int* __restrict__ bins,
                                                   const int* __restrict__ tail,
                                                   unsigned* __restrict__ wdesc,
                                                   int* __restrict__ col,
                                                   float* __restrict__ dinv, int n) {
  __shared__ int hist[BSPAN], lpre[BSPAN], lcur[BSPAN], sd[BLK];
  const int b = blockIdx.x, tid = threadIdx.x;
  const int cnt = tail[b];
  const int base = b * CAP2;
  const int node0 = b << BSHIFT;
  const int nNodes = min(BSPAN, n - node0);
  const int* bin = bins + (size_t)b * CAP;

  hist[tid] = 0; hist[tid + BLK] = 0;
  lcur[tid] = 0; lcur[tid + BLK] = 0;
  __syncthreads();
  for (int j = tid; j < cnt; j += BLK) atomicAdd(&hist[(unsigned)bin[j] >> 23], 1);
  __syncthreads();
  // exclusive scan over PADDED counts (2 per thread)
  int h0 = hist[2 * tid], h1 = hist[2 * tid + 1];
  int p0 = (h0 + 7) & ~7, p1 = (h1 + 7) & ~7;
  int ts = p0 + p1;
  sd[tid] = ts;
  __syncthreads();
  for (int off = 1; off < BLK; off <<= 1) {
    int t = (tid >= off) ? sd[tid - off] : 0;
    __syncthreads();
    sd[tid] += t;
    __syncthreads();
  }
  int ex = sd[tid] - ts;
  lpre[2 * tid] = ex;
  lpre[2 * tid + 1] = ex + p0;
  __syncthreads();
  for (int d = tid; d < nNodes; d += BLK) {
    int hd = hist[d];
    int begd = base + lpre[d];
    wdesc[node0 + d] = ((unsigned)begd << 10) | (unsigned)((hd + 7) >> 3);
    dinv[node0 + d] = rsqrtf((float)hd + 1.0f);
    int pe = (hd + 7) & ~7;
    for (int t = hd; t < pe; t++) col[begd + t] = n;  // pad -> zero row
  }
  __syncthreads();
  for (int j = tid; j < cnt; j += BLK) {
    int pkv = bin[j];
    int dlo = (unsigned)pkv >> 23;
    int idx = atomicAdd(&lcur[dlo], 1);
    col[base + lpre[dlo] + idx] = pkv & 0x7FFFFF;
  }
}

// ---------------- MFMA GEMM via split-bf16: G = bf16((X @ W) * dinv) ----------------
// 3 MFMA per tile (hi*hi + lo*hi + hi*lo); fp32-grade accuracy. Block 0 also
// zeroes the pad row G[n][*] (read by agg for padded slots).
template <int K, int M>
__global__ void __launch_bounds__(BLK) gemm_mfma(const float* __restrict__ X,
                                                 const float* __restrict__ W,
                                                 const float* __restrict__ dinv,
                                                 u16* __restrict__ G, int n) {
  constexpr int KC = K / 32;   // K-chunks
  constexpr int CT = M / 16;   // 16-col tiles
  constexpr int PADK = K + 8;  // row stride 272B (K=128): 2-way bank alias = free
  __shared__ u16 wt_hi[M][PADK];
  __shared__ u16 wt_lo[M][PADK];
  const int tid = threadIdx.x;
  const int lane = tid & 63;
  const int wv = tid >> 6;

  if (blockIdx.x == 0 && tid < M) G[(size_t)n * M + tid] = 0;  // zero pad row

  // stage W transposed + hi/lo split (one-time; reads coalesced)
  for (int i = tid; i < K * M; i += BLK) {
    int k = i / M, m = i % M;
    float w = W[i];
    unsigned wb = __float_as_uint(w);
    wt_hi[m][k] = (u16)(wb >> 16);                       // truncation hi
    wt_lo[m][k] = f2bf(w - __uint_as_float(wb & 0xFFFF0000u));
  }
  __syncthreads();

  const int r16 = lane & 15;
  const int oct = lane >> 4;
  int rowA = blockIdx.x * 64 + wv * 16 + r16;
  if (rowA >= n) rowA = n - 1;  // clamp (stores guarded)

  f32x4 acc[CT];
#pragma unroll
  for (int ct = 0; ct < CT; ct++) acc[ct] = (f32x4){0.f, 0.f, 0.f, 0.f};

#pragma unroll
  for (int kc = 0; kc < KC; kc++) {
    const float* xp = &X[(size_t)rowA * K + kc * 32 + oct * 8];
    float4 v0 = *(const float4*)xp;
    float4 v1 = *(const float4*)(xp + 4);
    float vv[8] = {v0.x, v0.y, v0.z, v0.w, v1.x, v1.y, v1.z, v1.w};
    short8_t ahi, alo;
#pragma unroll
    for (int j = 0; j < 8; j++) {
      unsigned xb = __float_as_uint(vv[j]);
      ahi[j] = (short)(xb >> 16);  // truncation hi
      alo[j] = (short)f2bf(vv[j] - __uint_as_float(xb & 0xFFFF0000u));
    }
#pragma unroll
    for (int ct = 0; ct < CT; ct++) {
      short8_t bhi = *(const short8_t*)&wt_hi[ct * 16 + r16][kc * 32 + oct * 8];
      short8_t blo = *(const short8_t*)&wt_lo[ct * 16 + r16][kc * 32 + oct * 8];
      acc[ct] = __builtin_amdgcn_mfma_f32_16x16x32_bf16(ahi, bhi, acc[ct], 0, 0, 0);
      acc[ct] = __builtin_amdgcn_mfma_f32_16x16x32_bf16(alo, bhi, acc[ct], 0, 0, 0);
      acc[ct] = __builtin_amdgcn_mfma_f32_16x16x32_bf16(ahi, blo, acc[ct], 0, 0, 0);
    }
  }

  // epilogue: C row = oct*4 + reg, col = ct*16 + r16
  const int rbase = blockIdx.x * 64 + wv * 16 + oct * 4;
  float dv[4];
#pragma unroll
  for (int r = 0; r < 4; r++) {
    int gr = rbase + r;
    dv[r] = (gr < n) ? dinv[gr] : 0.f;
  }
#pragma unroll
  for (int ct = 0; ct < CT; ct++) {
#pragma unroll
    for (int r = 0; r < 4; r++) {
      int gr = rbase + r;
      if (gr < n) G[(size_t)gr * M + ct * 16 + r16] = f2bf(acc[ct][r] * dv[r]);
    }
  }
}

// ---------------- aggregation (2 nodes per wave) ----------------
// gs (bf16, N+1 rows; row n zero). Segments padded to mult-of-8 with col=n.
// Wave = 2 half-waves; each half owns one node. Per iter one int4/int2 col
// load + 4/2 row gathers serve 8 neighbors per node.

__global__ void __launch_bounds__(BLK) agg1_kernel(const u16* __restrict__ gs,
                                                   const unsigned* __restrict__ wdesc,
                                                   const int* __restrict__ col,
                                                   const float* __restrict__ dinv,
                                                   const float* __restrict__ bias,
                                                   float* __restrict__ out, int n) {
  const int wv = threadIdx.x >> 6;
  const int lane = threadIdx.x & 63;
  const int half = lane >> 5;
  const int hl = lane & 31;
  const int node = blockIdx.x * 8 + wv * 2 + half;
  const int nodec = node < n ? node : n - 1;
  const int q = hl >> 4;    // neighbor sub-batch (0..1): 4 neighbors each
  const int cs = hl & 15;   // channel slice (4 ch)
  unsigned w = wdesc[nodec];
  int beg = (int)(w >> 10), nb = (int)(w & 1023);
  float a0, a1, a2, a3;
  {  // self-loop slice (q==0 only)
    uint2 u = *(const uint2*)&gs[(size_t)nodec * 64 + cs * 4];
    float m = (q == 0) ? 1.f : 0.f;
    a0 = m * bf_lo(u.x); a1 = m * bf_hi(u.x);
    a2 = m * bf_lo(u.y); a3 = m * bf_hi(u.y);
  }
  for (int i = 0; i < nb; i++) {
    int4 s4 = *(const int4*)&col[beg + i * 8 + q * 4];  // 16B aligned (8-padded)
    uint2 u0 = *(const uint2*)&gs[(size_t)s4.x * 64 + cs * 4];
    uint2 u1 = *(const uint2*)&gs[(size_t)s4.y * 64 + cs * 4];
    uint2 u2 = *(const uint2*)&gs[(size_t)s4.z * 64 + cs * 4];
    uint2 u3 = *(const uint2*)&gs[(size_t)s4.w * 64 + cs * 4];
    a0 += bf_lo(u0.x); a1 += bf_hi(u0.x); a2 += bf_lo(u0.y); a3 += bf_hi(u0.y);
    a0 += bf_lo(u1.x); a1 += bf_hi(u1.x); a2 += bf_lo(u1.y); a3 += bf_hi(u1.y);
    a0 += bf_lo(u2.x); a1 += bf_hi(u2.x); a2 += bf_lo(u2.y); a3 += bf_hi(u2.y);
    a0 += bf_lo(u3.x); a1 += bf_hi(u3.x); a2 += bf_lo(u3.y); a3 += bf_hi(u3.y);
  }
  // fold q within each half
  a0 += __shfl_xor(a0, 16); a1 += __shfl_xor(a1, 16);
  a2 += __shfl_xor(a2, 16); a3 += __shfl_xor(a3, 16);
  if (q == 0 && node < n) {
    float di = dinv[node];
    float4 bv = *(const float4*)&bias[cs * 4];
    float4 o;
    o.x = a0 * di + bv.x; o.y = a1 * di + bv.y;
    o.z = a2 * di + bv.z; o.w = a3 * di + bv.w;
    o.x = o.x > 0.f ? o.x : 0.f;
    o.y = o.y > 0.f ? o.y : 0.f;
    o.z = o.z > 0.f ? o.z : 0.f;
    o.w = o.w > 0.f ? o.w : 0.f;
    *(float4*)&out[(size_t)node * 64 + cs * 4] = o;
  }
}

__global__ void __launch_bounds__(BLK) agg2_kernel(const u16* __restrict__ gs,
                                                   const unsigned* __restrict__ wdesc,
                                                   const int* __restrict__ col,
                                                   const float* __restrict__ dinv,
                                                   const float* __restrict__ bias,
                                                   float* __restrict__ out, int n) {
  const int wv = threadIdx.x >> 6;
  const int lane = threadIdx.x & 63;
  const int half = lane >> 5;
  const int hl = lane & 31;
  const int node = blockIdx.x * 8 + wv * 2 + half;
  const int nodec = node < n ? node : n - 1;
  const int q = hl >> 3;    // neighbor sub-batch (0..3): 2 neighbors each
  const int cs = hl & 7;    // channel slice (4 ch)
  unsigned w = wdesc[nodec];
  int beg = (int)(w >> 10), nb = (int)(w & 1023);
  float a0, a1, a2, a3;
  {
    uint2 u = *(const uint2*)&gs[(size_t)nodec * 32 + cs * 4];
    float m = (q == 0) ? 1.f : 0.f;
    a0 = m * bf_lo(u.x); a1 = m * bf_hi(u.x);
    a2 = m * bf_lo(u.y); a3 = m * bf_hi(u.y);
  }
  for (int i = 0; i < nb; i++) {
    int2 s2 = *(const int2*)&col[beg + i * 8 + q * 2];  // 8B aligned
    uint2 u0 = *(const uint2*)&gs[(size_t)s2.x * 32 + cs * 4];
    uint2 u1 = *(const uint2*)&gs[(size_t)s2.y * 32 + cs * 4];
    a0 += bf_lo(u0.x); a1 += bf_hi(u0.x); a2 += bf_lo(u0.y); a3 += bf_hi(u0.y);
    a0 += bf_lo(u1.x); a1 += bf_hi(u1.x); a2 += bf_lo(u1.y); a3 += bf_hi(u1.y);
  }
  a0 += __shfl_xor(a0, 8);  a1 += __shfl_xor(a1, 8);
  a2 += __shfl_xor(a2, 8);  a3 += __shfl_xor(a3, 8);
  a0 += __shfl_xor(a0, 16); a1 += __shfl_xor(a1, 16);
  a2 += __shfl_xor(a2, 16); a3 += __shfl_xor(a3, 16);
  if (q == 0 && node < n) {
    float di = dinv[node];
    float4 bv = *(const float4*)&bias[cs * 4];
    float4 o;
    o.x = a0 * di + bv.x; o.y = a1 * di + bv.y;
    o.z = a2 * di + bv.z; o.w = a3 * di + bv.w;
    o.x = o.x > 0.f ? o.x : 0.f;
    o.y = o.y > 0.f ? o.y : 0.f;
    o.z = o.z > 0.f ? o.z : 0.f;
    o.w = o.w > 0.f ? o.w : 0.f;
    *(float4*)&out[(size_t)node * 32 + cs * 4] = o;
  }
}

// ---------------- launcher ----------------

extern "C" void kernel_launch(void* const* d_in, const int* in_sizes, int n_in,
                              void* d_out, int out_size, void* d_ws, size_t ws_size,
                              hipStream_t stream) {
  const float* x = (const float*)d_in[0];
  const int* ei = (const int*)d_in[1];
  const float* W1 = (const float*)d_in[2];
  const float* b1 = (const float*)d_in[3];
  const float* W2 = (const float*)d_in[4];
  const float* b2 = (const float*)d_in[5];

  const int N = in_sizes[0] / 128;
  const int E = in_sizes[1] / 2;
  const int* src = ei;
  const int* dst = ei + E;
  const int nb = (N + BSPAN - 1) >> BSHIFT;  // # coarse buckets (196 @ N=100K)

  char* p = (char*)d_ws;
  auto take = [&](size_t bytes) -> char* {
    char* q = p;
    p += (bytes + 255) & ~(size_t)255;
    return q;
  };
  int* bins = (int*)take((size_t)NB_MAX * CAP * 4);
  int* tail = (int*)take(NB_MAX * 4);
  unsigned* wdesc = (unsigned*)take((size_t)N * 4);
  int* col = (int*)take((size_t)nb * CAP2 * 4);
  float* dinv = (float*)take((size_t)N * 4);
  u16* g1 = (u16*)take((size_t)(N + 1) * 64 * 2);  // +1 zero row
  float* h = (float*)take((size_t)N * 64 * 4);
  u16* g2 = (u16*)take((size_t)(N + 1) * 32 * 2);  // +1 zero row

  hipMemsetAsync(tail, 0, NB_MAX * 4, stream);

  binpass<<<(E + EPBB - 1) / EPBB, BLK, 0, stream>>>(src, dst, E, bins, tail);
  bucket_sort<<<nb, BLK, 0, stream>>>(bins, tail, wdesc, col, dinv, N);

  gemm_mfma<128, 64><<<(N + 63) / 64, BLK, 0, stream>>>(x, W1, dinv, g1, N);
  agg1_kernel<<<(N + 7) / 8, BLK, 0, stream>>>(g1, wdesc, col, dinv, b1, h, N);
  gemm_mfma<64, 32><<<(N + 63) / 64, BLK, 0, stream>>>(h, W2, dinv, g2, N);
  agg2_kernel<<<(N + 7) / 8, BLK, 0, stream>>>(g2, wdesc, col, dinv, b2, (float*)d_out, N);
}

// Round 14
// 138.478 us; speedup vs baseline: 2.9011x; 1.0606x over previous
//
#include <hip/hip_runtime.h>
#include <math.h>

constexpr int BLK = 256;
constexpr int NB_MAX = 256;      // max coarse buckets (supports N <= 131072)
constexpr int BSHIFT = 9;        // 512 nodes per bucket
constexpr int BSPAN = 1 << BSHIFT;
constexpr int CAP = 10240;       // per-bucket bin capacity (mean 8192 @ E=1.6M, +22 sigma)
constexpr int CAP2 = 12800;      // per-bucket padded col capacity (mean 9984, +31 sigma)
constexpr int EPT2 = 16;         // edges per thread in binpass
constexpr int EPBB = BLK * EPT2; // 4096 edges per block

typedef unsigned short u16;
typedef __attribute__((ext_vector_type(8))) short short8_t;
typedef __attribute__((ext_vector_type(4))) float f32x4;

// ---- bf16 helpers ----
__device__ __forceinline__ u16 f2bf(float f) {
  union { float f; unsigned int i; } v;
  v.f = f;
  unsigned int r = v.i + 0x7FFF + ((v.i >> 16) & 1);  // RNE
  return (u16)(r >> 16);
}
__device__ __forceinline__ float bf_lo(unsigned u) {
  union { unsigned int i; float f; } v;
  v.i = u << 16;
  return v.f;
}
__device__ __forceinline__ float bf_hi(unsigned u) {
  union { unsigned int i; float f; } v;
  v.i = u & 0xFFFF0000u;
  return v.f;
}

// ---------------- pass 1: coarse binning into block-private chunks ----------------
__global__ void __launch_bounds__(BLK) binpass(const int* __restrict__ src,
                                               const int* __restrict__ dst,
                                               int e, int* __restrict__ bins,
                                               int* __restrict__ tail) {
  __shared__ int lcnt[NB_MAX], gbase[NB_MAX], lcur[NB_MAX];
  const int tid = threadIdx.x;
  lcnt[tid] = 0;
  lcur[tid] = 0;
  __syncthreads();
  const int i0 = blockIdx.x * EPBB;
  int bb[EPT2], pk[EPT2];
#pragma unroll
  for (int k = 0; k < EPT2; k++) {
    int i = i0 + k * BLK + tid;
    if (i < e) {
      int d = dst[i], s = src[i];
      bb[k] = d >> BSHIFT;
      pk[k] = ((d & (BSPAN - 1)) << 23) | s;   // src < 2^23, dlo < 2^9
      atomicAdd(&lcnt[bb[k]], 1);
    } else {
      bb[k] = -1;
    }
  }
  __syncthreads();
  gbase[tid] = atomicAdd(&tail[tid], lcnt[tid]);  // reserve contiguous chunk per bucket
  __syncthreads();
#pragma unroll
  for (int k = 0; k < EPT2; k++) {
    if (bb[k] >= 0) {
      int idx = atomicAdd(&lcur[bb[k]], 1);
      bins[bb[k] * CAP + gbase[bb[k]] + idx] = pk[k];
    }
  }
}

// ---------------- pass 2: per-bucket counting sort into FIXED col region ----------------
// Bucket b owns col[b*CAP2 .. b*CAP2+CAP2). Per-node segments padded to mult-of-8
// with pad entries = n (zero row). wdesc[node] = (beg<<10) | ceil(deg/8).
__global__ void __launch_bounds__(BLK) bucket_sort(const int* __restrict__ bins,
                                                   const int* __restrict__ tail,
                                                   unsigned* __restrict__ wdesc,
                                                   int* __restrict__ col,
                                                   float* __restrict__ dinv, int n) {
  __shared__ int hist[BSPAN], lpre[BSPAN], lcur[BSPAN], sd[BLK];
  const int b = blockIdx.x, tid = threadIdx.x;
  const int cnt = tail[b];
  const int base = b * CAP2;
  const int node0 = b << BSHIFT;
  const int nNodes = min(BSPAN, n - node0);
  const int* bin = bins + (size_t)b * CAP;

  hist[tid] = 0; hist[tid + BLK] = 0;
  lcur[tid] = 0; lcur[tid + BLK] = 0;
  __syncthreads();
  for (int j = tid; j < cnt; j += BLK) atomicAdd(&hist[(unsigned)bin[j] >> 23], 1);
  __syncthreads();
  // exclusive scan over PADDED counts (2 per thread)
  int h0 = hist[2 * tid], h1 = hist[2 * tid + 1];
  int p0 = (h0 + 7) & ~7, p1 = (h1 + 7) & ~7;
  int ts = p0 + p1;
  sd[tid] = ts;
  __syncthreads();
  for (int off = 1; off < BLK; off <<= 1) {
    int t = (tid >= off) ? sd[tid - off] : 0;
    __syncthreads();
    sd[tid] += t;
    __syncthreads();
  }
  int ex = sd[tid] - ts;
  lpre[2 * tid] = ex;
  lpre[2 * tid + 1] = ex + p0;
  __syncthreads();
  for (int d = tid; d < nNodes; d += BLK) {
    int hd = hist[d];
    int begd = base + lpre[d];
    wdesc[node0 + d] = ((unsigned)begd << 10) | (unsigned)((hd + 7) >> 3);
    dinv[node0 + d] = rsqrtf((float)hd + 1.0f);
    int pe = (hd + 7) & ~7;
    for (int t = hd; t < pe; t++) col[begd + t] = n;  // pad -> zero row
  }
  __syncthreads();
  for (int j = tid; j < cnt; j += BLK) {
    int pkv = bin[j];
    int dlo = (unsigned)pkv >> 23;
    int idx = atomicAdd(&lcur[dlo], 1);
    col[base + lpre[dlo] + idx] = pkv & 0x7FFFFF;
  }
}

// ---------------- MFMA GEMM via split-bf16: G = bf16((X @ W) * dinv) ----------------
// 3 MFMA per tile (hi*hi + lo*hi + hi*lo); fp32-grade accuracy. Block 0 also
// zeroes the pad row G[n][*] (read by agg for padded slots).
template <int K, int M>
__global__ void __launch_bounds__(BLK) gemm_mfma(const float* __restrict__ X,
                                                 const float* __restrict__ W,
                                                 const float* __restrict__ dinv,
                                                 u16* __restrict__ G, int n) {
  constexpr int KC = K / 32;   // K-chunks
  constexpr int CT = M / 16;   // 16-col tiles
  constexpr int PADK = K + 8;  // row stride 272B (K=128): 2-way bank alias = free
  __shared__ u16 wt_hi[M][PADK];
  __shared__ u16 wt_lo[M][PADK];
  const int tid = threadIdx.x;
  const int lane = tid & 63;
  const int wv = tid >> 6;

  if (blockIdx.x == 0 && tid < M) G[(size_t)n * M + tid] = 0;  // zero pad row

  // stage W transposed + hi/lo split (one-time; reads coalesced)
  for (int i = tid; i < K * M; i += BLK) {
    int k = i / M, m = i % M;
    float w = W[i];
    unsigned wb = __float_as_uint(w);
    wt_hi[m][k] = (u16)(wb >> 16);                       // truncation hi
    wt_lo[m][k] = f2bf(w - __uint_as_float(wb & 0xFFFF0000u));
  }
  __syncthreads();

  const int r16 = lane & 15;
  const int oct = lane >> 4;
  int rowA = blockIdx.x * 64 + wv * 16 + r16;
  if (rowA >= n) rowA = n - 1;  // clamp (stores guarded)

  f32x4 acc[CT];
#pragma unroll
  for (int ct = 0; ct < CT; ct++) acc[ct] = (f32x4){0.f, 0.f, 0.f, 0.f};

#pragma unroll
  for (int kc = 0; kc < KC; kc++) {
    const float* xp = &X[(size_t)rowA * K + kc * 32 + oct * 8];
    float4 v0 = *(const float4*)xp;
    float4 v1 = *(const float4*)(xp + 4);
    float vv[8] = {v0.x, v0.y, v0.z, v0.w, v1.x, v1.y, v1.z, v1.w};
    short8_t ahi, alo;
#pragma unroll
    for (int j = 0; j < 8; j++) {
      unsigned xb = __float_as_uint(vv[j]);
      ahi[j] = (short)(xb >> 16);  // truncation hi
      alo[j] = (short)f2bf(vv[j] - __uint_as_float(xb & 0xFFFF0000u));
    }
#pragma unroll
    for (int ct = 0; ct < CT; ct++) {
      short8_t bhi = *(const short8_t*)&wt_hi[ct * 16 + r16][kc * 32 + oct * 8];
      short8_t blo = *(const short8_t*)&wt_lo[ct * 16 + r16][kc * 32 + oct * 8];
      acc[ct] = __builtin_amdgcn_mfma_f32_16x16x32_bf16(ahi, bhi, acc[ct], 0, 0, 0);
      acc[ct] = __builtin_amdgcn_mfma_f32_16x16x32_bf16(alo, bhi, acc[ct], 0, 0, 0);
      acc[ct] = __builtin_amdgcn_mfma_f32_16x16x32_bf16(ahi, blo, acc[ct], 0, 0, 0);
    }
  }

  // epilogue: C row = oct*4 + reg, col = ct*16 + r16
  const int rbase = blockIdx.x * 64 + wv * 16 + oct * 4;
  float dv[4];
#pragma unroll
  for (int r = 0; r < 4; r++) {
    int gr = rbase + r;
    dv[r] = (gr < n) ? dinv[gr] : 0.f;
  }
#pragma unroll
  for (int ct = 0; ct < CT; ct++) {
#pragma unroll
    for (int r = 0; r < 4; r++) {
      int gr = rbase + r;
      if (gr < n) G[(size_t)gr * M + ct * 16 + r16] = f2bf(acc[ct][r] * dv[r]);
    }
  }
}

// ---------------- aggregation (one node per lane-group, no shuffles) ----------------
// gs (bf16, N+1 rows; row n zero). Segments padded to mult-of-8 with col=n.

// layer 1: 16 lanes per node (cs = 4-channel slice). Per iter: 2 broadcast int4
// col loads + 8 row gathers (128B line each) + 32 unpack-adds per lane.
__global__ void __launch_bounds__(BLK) agg1_kernel(const u16* __restrict__ gs,
                                                   const unsigned* __restrict__ wdesc,
                                                   const int* __restrict__ col,
                                                   const float* __restrict__ dinv,
                                                   const float* __restrict__ bias,
                                                   float* __restrict__ out, int n) {
  const int tid = threadIdx.x;
  const int node = blockIdx.x * 16 + (tid >> 4);
  if (node >= n) return;
  const int cs = tid & 15;
  unsigned w = wdesc[node];
  int beg = (int)(w >> 10), nb = (int)(w & 1023);
  float a0, a1, a2, a3;
  {  // self-loop slice (unconditional: this group owns the node)
    uint2 u = *(const uint2*)&gs[(size_t)node * 64 + cs * 4];
    a0 = bf_lo(u.x); a1 = bf_hi(u.x); a2 = bf_lo(u.y); a3 = bf_hi(u.y);
  }
  for (int i = 0; i < nb; i++) {
    int j = beg + i * 8;
    int4 sA = *(const int4*)&col[j];
    int4 sB = *(const int4*)&col[j + 4];
    uint2 u0 = *(const uint2*)&gs[(size_t)sA.x * 64 + cs * 4];
    uint2 u1 = *(const uint2*)&gs[(size_t)sA.y * 64 + cs * 4];
    uint2 u2 = *(const uint2*)&gs[(size_t)sA.z * 64 + cs * 4];
    uint2 u3 = *(const uint2*)&gs[(size_t)sA.w * 64 + cs * 4];
    uint2 u4 = *(const uint2*)&gs[(size_t)sB.x * 64 + cs * 4];
    uint2 u5 = *(const uint2*)&gs[(size_t)sB.y * 64 + cs * 4];
    uint2 u6 = *(const uint2*)&gs[(size_t)sB.z * 64 + cs * 4];
    uint2 u7 = *(const uint2*)&gs[(size_t)sB.w * 64 + cs * 4];
    a0 += bf_lo(u0.x); a1 += bf_hi(u0.x); a2 += bf_lo(u0.y); a3 += bf_hi(u0.y);
    a0 += bf_lo(u1.x); a1 += bf_hi(u1.x); a2 += bf_lo(u1.y); a3 += bf_hi(u1.y);
    a0 += bf_lo(u2.x); a1 += bf_hi(u2.x); a2 += bf_lo(u2.y); a3 += bf_hi(u2.y);
    a0 += bf_lo(u3.x); a1 += bf_hi(u3.x); a2 += bf_lo(u3.y); a3 += bf_hi(u3.y);
    a0 += bf_lo(u4.x); a1 += bf_hi(u4.x); a2 += bf_lo(u4.y); a3 += bf_hi(u4.y);
    a0 += bf_lo(u5.x); a1 += bf_hi(u5.x); a2 += bf_lo(u5.y); a3 += bf_hi(u5.y);
    a0 += bf_lo(u6.x); a1 += bf_hi(u6.x); a2 += bf_lo(u6.y); a3 += bf_hi(u6.y);
    a0 += bf_lo(u7.x); a1 += bf_hi(u7.x); a2 += bf_lo(u7.y); a3 += bf_hi(u7.y);
  }
  float di = dinv[node];
  float4 bv = *(const float4*)&bias[cs * 4];
  float4 o;
  o.x = a0 * di + bv.x; o.y = a1 * di + bv.y;
  o.z = a2 * di + bv.z; o.w = a3 * di + bv.w;
  o.x = o.x > 0.f ? o.x : 0.f;
  o.y = o.y > 0.f ? o.y : 0.f;
  o.z = o.z > 0.f ? o.z : 0.f;
  o.w = o.w > 0.f ? o.w : 0.f;
  *(float4*)&out[(size_t)node * 64 + cs * 4] = o;
}

// layer 2: 8 lanes per node (cs = 4-channel slice of 32). Same batch structure.
__global__ void __launch_bounds__(BLK) agg2_kernel(const u16* __restrict__ gs,
                                                   const unsigned* __restrict__ wdesc,
                                                   const int* __restrict__ col,
                                                   const float* __restrict__ dinv,
                                                   const float* __restrict__ bias,
                                                   float* __restrict__ out, int n) {
  const int tid = threadIdx.x;
  const int node = blockIdx.x * 32 + (tid >> 3);
  if (node >= n) return;
  const int cs = tid & 7;
  unsigned w = wdesc[node];
  int beg = (int)(w >> 10), nb = (int)(w & 1023);
  float a0, a1, a2, a3;
  {
    uint2 u = *(const uint2*)&gs[(size_t)node * 32 + cs * 4];
    a0 = bf_lo(u.x); a1 = bf_hi(u.x); a2 = bf_lo(u.y); a3 = bf_hi(u.y);
  }
  for (int i = 0; i < nb; i++) {
    int j = beg + i * 8;
    int4 sA = *(const int4*)&col[j];
    int4 sB = *(const int4*)&col[j + 4];
    uint2 u0 = *(const uint2*)&gs[(size_t)sA.x * 32 + cs * 4];
    uint2 u1 = *(const uint2*)&gs[(size_t)sA.y * 32 + cs * 4];
    uint2 u2 = *(const uint2*)&gs[(size_t)sA.z * 32 + cs * 4];
    uint2 u3 = *(const uint2*)&gs[(size_t)sA.w * 32 + cs * 4];
    uint2 u4 = *(const uint2*)&gs[(size_t)sB.x * 32 + cs * 4];
    uint2 u5 = *(const uint2*)&gs[(size_t)sB.y * 32 + cs * 4];
    uint2 u6 = *(const uint2*)&gs[(size_t)sB.z * 32 + cs * 4];
    uint2 u7 = *(const uint2*)&gs[(size_t)sB.w * 32 + cs * 4];
    a0 += bf_lo(u0.x); a1 += bf_hi(u0.x); a2 += bf_lo(u0.y); a3 += bf_hi(u0.y);
    a0 += bf_lo(u1.x); a1 += bf_hi(u1.x); a2 += bf_lo(u1.y); a3 += bf_hi(u1.y);
    a0 += bf_lo(u2.x); a1 += bf_hi(u2.x); a2 += bf_lo(u2.y); a3 += bf_hi(u2.y);
    a0 += bf_lo(u3.x); a1 += bf_hi(u3.x); a2 += bf_lo(u3.y); a3 += bf_hi(u3.y);
    a0 += bf_lo(u4.x); a1 += bf_hi(u4.x); a2 += bf_lo(u4.y); a3 += bf_hi(u4.y);
    a0 += bf_lo(u5.x); a1 += bf_hi(u5.x); a2 += bf_lo(u5.y); a3 += bf_hi(u5.y);
    a0 += bf_lo(u6.x); a1 += bf_hi(u6.x); a2 += bf_lo(u6.y); a3 += bf_hi(u6.y);
    a0 += bf_lo(u7.x); a1 += bf_hi(u7.x); a2 += bf_lo(u7.y); a3 += bf_hi(u7.y);
  }
  float di = dinv[node];
  float4 bv = *(const float4*)&bias[cs * 4];
  float4 o;
  o.x = a0 * di + bv.x; o.y = a1 * di + bv.y;
  o.z = a2 * di + bv.z; o.w = a3 * di + bv.w;
  o.x = o.x > 0.f ? o.x : 0.f;
  o.y = o.y > 0.f ? o.y : 0.f;
  o.z = o.z > 0.f ? o.z : 0.f;
  o.w = o.w > 0.f ? o.w : 0.f;
  *(float4*)&out[(size_t)node * 32 + cs * 4] = o;
}

// ---------------- launcher ----------------

extern "C" void kernel_launch(void* const* d_in, const int* in_sizes, int n_in,
                              void* d_out, int out_size, void* d_ws, size_t ws_size,
                              hipStream_t stream) {
  const float* x = (const float*)d_in[0];
  const int* ei = (const int*)d_in[1];
  const float* W1 = (const float*)d_in[2];
  const float* b1 = (const float*)d_in[3];
  const float* W2 = (const float*)d_in[4];
  const float* b2 = (const float*)d_in[5];

  const int N = in_sizes[0] / 128;
  const int E = in_sizes[1] / 2;
  const int* src = ei;
  const int* dst = ei + E;
  const int nb = (N + BSPAN - 1) >> BSHIFT;  // # coarse buckets (196 @ N=100K)

  char* p = (char*)d_ws;
  auto take = [&](size_t bytes) -> char* {
    char* q = p;
    p += (bytes + 255) & ~(size_t)255;
    return q;
  };
  int* bins = (int*)take((size_t)NB_MAX * CAP * 4);
  int* tail = (int*)take(NB_MAX * 4);
  unsigned* wdesc = (unsigned*)take((size_t)N * 4);
  int* col = (int*)take((size_t)nb * CAP2 * 4);
  float* dinv = (float*)take((size_t)N * 4);
  u16* g1 = (u16*)take((size_t)(N + 1) * 64 * 2);  // +1 zero row
  float* h = (float*)take((size_t)N * 64 * 4);
  u16* g2 = (u16*)take((size_t)(N + 1) * 32 * 2);  // +1 zero row

  hipMemsetAsync(tail, 0, NB_MAX * 4, stream);

  binpass<<<(E + EPBB - 1) / EPBB, BLK, 0, stream>>>(src, dst, E, bins, tail);
  bucket_sort<<<nb, BLK, 0, stream>>>(bins, tail, wdesc, col, dinv, N);

  gemm_mfma<128, 64><<<(N + 63) / 64, BLK, 0, stream>>>(x, W1, dinv, g1, N);
  agg1_kernel<<<(N + 15) / 16, BLK, 0, stream>>>(g1, wdesc, col, dinv, b1, h, N);
  gemm_mfma<64, 32><<<(N + 63) / 64, BLK, 0, stream>>>(h, W2, dinv, g2, N);
  agg2_kernel<<<(N + 31) / 32, BLK, 0, stream>>>(g2, wdesc, col, dinv, b2, (float*)d_out, N);
}